// Round 2
// baseline (814.276 us; speedup 1.0000x reference)
//
#include <hip/hip_runtime.h>
#include <stdint.h>

typedef short short8 __attribute__((ext_vector_type(8)));
typedef float floatx4 __attribute__((ext_vector_type(4)));
typedef unsigned short ushort_t;

#define BATCH 32768
#define STR   232          // LDS row stride in bf16 elems (16 rows per wave slab)
#define SLAB  (16*STR)     // 3712 ushorts = 7424 B per buffer
#define TOT_TILES 1391     // ws need = TOT_TILES * 1024 B = 1.42 MB

// matrix ids (order matches convw src[] and TILE0)
#define M_SA 0
#define M_IR 1
#define M_HR 2
#define M_IZ 3
#define M_HZ 4
#define M_IN 5
#define M_HN 6
#define M_BP 7
#define M_SP 8
#define M_SQ 9
#define M_BQ 10

__device__ constexpr int TILE0[11] = {0,65,156,247,338,429,520,611,702,793,884};
__device__ constexpr int KLIM[11]  = {132,200,200,200,200,200,200,200,200,200,0};

__device__ __forceinline__ ushort_t f2bf(float f){
  uint32_t u = __float_as_uint(f);
  uint32_t r = (u + 0x7fffu + ((u >> 16) & 1u)) >> 16;   // RNE
  return (ushort_t)r;
}
__device__ __forceinline__ float bf2f(ushort_t h){ return __uint_as_float(((uint32_t)h) << 16); }

__device__ __forceinline__ float sigmf_(float x){ return 1.f / (1.f + expf(-x)); }
__device__ __forceinline__ float softplusf_(float x){
  return fmaxf(x, 0.f) + log1pf(expf(-fabsf(x)));
}
__device__ __forceinline__ uint32_t rotl32(uint32_t x, int r){ return (x << r) | (x >> (32 - r)); }

__device__ __forceinline__ void threefry2x32_k42(uint32_t x0, uint32_t x1,
                                                 uint32_t& o0, uint32_t& o1){
  const uint32_t k0 = 0u, k1 = 42u, k2 = 0u ^ 42u ^ 0x1BD11BDAu;
  x0 += k0; x1 += k1;
#define TF_R(rot) { x0 += x1; x1 = rotl32(x1, rot); x1 ^= x0; }
  TF_R(13) TF_R(15) TF_R(26) TF_R(6)  x0 += k1; x1 += k2 + 1u;
  TF_R(17) TF_R(29) TF_R(16) TF_R(24) x0 += k2; x1 += k0 + 2u;
  TF_R(13) TF_R(15) TF_R(26) TF_R(6)  x0 += k0; x1 += k1 + 3u;
  TF_R(17) TF_R(29) TF_R(16) TF_R(24) x0 += k1; x1 += k2 + 4u;
  TF_R(13) TF_R(15) TF_R(26) TF_R(6)  x0 += k2; x1 += k0 + 5u;
#undef TF_R
  o0 = x0; o1 = x1;
}

__device__ __forceinline__ float jax_erfinv(float x){
  float w = -log1pf(-x * x);
  float p;
  if (w < 5.0f) {
    w -= 2.5f;
    p = 2.81022636e-08f;
    p = fmaf(p, w, 3.43273939e-07f);
    p = fmaf(p, w, -3.5233877e-06f);
    p = fmaf(p, w, -4.39150654e-06f);
    p = fmaf(p, w, 0.00021858087f);
    p = fmaf(p, w, -0.00125372503f);
    p = fmaf(p, w, -0.00417768164f);
    p = fmaf(p, w, 0.246640727f);
    p = fmaf(p, w, 1.50140941f);
  } else {
    w = sqrtf(w) - 3.0f;
    p = -0.000200214257f;
    p = fmaf(p, w, 0.000100950558f);
    p = fmaf(p, w, 0.00134934322f);
    p = fmaf(p, w, -0.00367342844f);
    p = fmaf(p, w, 0.00573950773f);
    p = fmaf(p, w, -0.0076224613f);
    p = fmaf(p, w, 0.00943887047f);
    p = fmaf(p, w, 1.00167406f);
    p = fmaf(p, w, 2.83297682f);
  }
  return p * x;
}

// partitionable threefry: counter=(0,j), bits = o0^o1  (verified passing R2)
__device__ __forceinline__ float jax_normal_at(uint32_t j){
  uint32_t o0, o1;
  threefry2x32_k42(0u, j, o0, o1);
  uint32_t bits = o0 ^ o1;
  const float lo = -0.99999994f;
  float f = __uint_as_float((bits >> 9) | 0x3f800000u) - 1.0f;
  float fm = f * 1.99999994f;
  float u = fmaxf(lo, fm + lo);
  return 1.41421356f * jax_erfinv(u);
}

// ---------------- weight conversion kernel (ws path only) ----------------
struct ConvP { const float* src[11]; ushort_t* dst; };

__global__ void __launch_bounds__(64) convw(ConvP cp)
{
  int t = blockIdx.x;
  int lane = threadIdx.x;
  const int cum[12] = {0,65,156,247,338,429,520,611,702,793,884,1391};
  int mi = 0;
  #pragma unroll
  for (int i = 0; i < 11; ++i) if (t >= cum[i+1]) mi = i+1;
  int lt = t - cum[mi];
  int kb = lt / 13, nt = lt - kb*13;
  const float* S = cp.src[mi];
  int q = lane >> 4, m = lane & 15;
  int n = nt*16 + m;
  ushort_t* D = cp.dst + (size_t)t*512 + lane*8;
  #pragma unroll
  for (int j = 0; j < 8; ++j){
    int k = kb*32 + q*8 + j;
    float v = 0.f;
    if (n < 200){
      if (mi == 10){                       // W_bq: k<200 nb rows; 200..223 zero; >=224 obs rows
        if (k < 200) v = S[k*200+n];
        else if (k >= 224) v = S[(size_t)(k-24)*200+n];
      } else {
        int K = (mi == 0) ? 132 : 200;
        if (k < K) v = S[k*200+n];
      }
    }
    D[j] = f2bf(v);
  }
}

// ---------------- main fused kernel ----------------
struct MainP {
  const float* prev_state; const float* prev_action; const float* prev_belief;
  const float* observation; const float* nonterm;
  const float* b_sa; const float* b_ir; const float* b_iz; const float* b_in; const float* b_hn;
  const float* b_bp; const float* b_sp; const float* b_bq; const float* b_sq;
  const float* W[11];          // fp32 weights by mat id (direct path)
  const ushort_t* ws;
  float* out;
};

__device__ __forceinline__ short8 afrag(const ushort_t* buf, int m, int kb, int q){
  return *(const short8*)(buf + m*STR + kb*32 + q*8);
}

// B-fragment: from bf16 ws (WS=1) or built from fp32 weights in-register (WS=0)
template<int MAT, int WS>
__device__ __forceinline__ short8 bfr(const MainP& p, int kb, int nt, int lane, int q, int m){
  if (WS){
    return *(const short8*)(p.ws + (((size_t)(TILE0[MAT] + kb*13 + nt)) << 9) + (lane << 3));
  } else {
    int n = nt*16 + m;
    const float* S = p.W[MAT];
    uint32_t u[8];
    #pragma unroll
    for (int j = 0; j < 8; ++j){
      int k = kb*32 + q*8 + j;
      int srow;
      if (MAT == M_BQ) srow = (k < 200) ? k : ((k >= 224) ? k - 24 : -1);
      else             srow = (k < KLIM[MAT]) ? k : -1;
      float v = (srow >= 0 && n < 200) ? S[(size_t)srow*200 + n] : 0.f;
      u[j] = __float_as_uint(v);
    }
    short8 r;
    #pragma unroll
    for (int j = 0; j < 8; ++j) r[j] = (short)(u[j] >> 16);  // truncate to bf16
    return r;
  }
}

// GRU column-chunk: 4 accumulator streams for CNT tiles; gates; writes nb to HBM
// AND keeps nb fp32 in nbv registers (bufX/bufH must stay intact for the other
// chunk's A-frag reads, so the LDS writeback happens after both chunks).
template<int WS, int CNT, int NT0>
__device__ __forceinline__ void gru_chunk(const MainP& p,
    const ushort_t* bufX, const ushort_t* bufH, int R0, int m, int q, int lane,
    floatx4 (&nbv)[13])
{
  floatx4 aR[CNT], aZ[CNT], aXN[CNT], aHN[CNT];
  #pragma unroll
  for (int i = 0; i < CNT; ++i){
    int col = (NT0+i)*16 + m;
    float br = (col<200)? p.b_ir[col] : 0.f;
    float bz = (col<200)? p.b_iz[col] : 0.f;
    float bn = (col<200)? p.b_in[col] : 0.f;
    float bh = (col<200)? p.b_hn[col] : 0.f;
    aR[i]  = (floatx4){br,br,br,br};
    aZ[i]  = (floatx4){bz,bz,bz,bz};
    aXN[i] = (floatx4){bn,bn,bn,bn};
    aHN[i] = (floatx4){bh,bh,bh,bh};
  }
  #pragma unroll 1
  for (int kb = 0; kb < 7; ++kb){
    short8 ax = afrag(bufX, m, kb, q);
    short8 ah = afrag(bufH, m, kb, q);
    #pragma unroll
    for (int i = 0; i < CNT; ++i){
      int nt = NT0 + i;
      aR[i]  = __builtin_amdgcn_mfma_f32_16x16x32_bf16(ax, bfr<M_IR,WS>(p,kb,nt,lane,q,m), aR[i], 0,0,0);
      aR[i]  = __builtin_amdgcn_mfma_f32_16x16x32_bf16(ah, bfr<M_HR,WS>(p,kb,nt,lane,q,m), aR[i], 0,0,0);
      aZ[i]  = __builtin_amdgcn_mfma_f32_16x16x32_bf16(ax, bfr<M_IZ,WS>(p,kb,nt,lane,q,m), aZ[i], 0,0,0);
      aZ[i]  = __builtin_amdgcn_mfma_f32_16x16x32_bf16(ah, bfr<M_HZ,WS>(p,kb,nt,lane,q,m), aZ[i], 0,0,0);
      aXN[i] = __builtin_amdgcn_mfma_f32_16x16x32_bf16(ax, bfr<M_IN,WS>(p,kb,nt,lane,q,m), aXN[i], 0,0,0);
      aHN[i] = __builtin_amdgcn_mfma_f32_16x16x32_bf16(ah, bfr<M_HN,WS>(p,kb,nt,lane,q,m), aHN[i], 0,0,0);
    }
  }
  #pragma unroll
  for (int i = 0; i < CNT; ++i){
    int col = (NT0+i)*16 + m;
    if (col < 200){
      #pragma unroll
      for (int rg = 0; rg < 4; ++rg){
        int rowl = q*4 + rg;
        float rr = sigmf_(aR[i][rg]);
        float zz = sigmf_(aZ[i][rg]);
        float nn = tanhf(fmaf(rr, aHN[i][rg], aXN[i][rg]));
        float hv = bf2f(bufH[rowl*STR + col]);
        float nb = fmaf(zz, hv - nn, nn);
        nbv[NT0+i][rg] = nb;
        __builtin_nontemporal_store(nb, &p.out[(size_t)(R0+rowl)*200 + col]);
      }
    }
  }
}

// head epilogue (verified passing R3 for prior): std transposed via fp32 LDS scratch
__device__ __forceinline__ void head_out(const floatx4* acc, float* sdb,
    float* o_state, float* o_mean, float* o_std, int R0, int m, int q)
{
  #pragma unroll
  for (int nt = 6; nt < 13; ++nt){
    int col = nt*16 + m;
    if (col >= 100 && col < 200){
      #pragma unroll
      for (int rg = 0; rg < 4; ++rg){
        int rowl = q*4 + rg;
        float sr = fmaxf(acc[nt][rg], 0.f);
        float sd = softplusf_(sr) + 0.1f;
        sdb[rowl*100 + (col-100)] = sd;
        __builtin_nontemporal_store(sd, &o_std[(size_t)(R0+rowl)*100 + (col-100)]);
      }
    }
  }
  __syncthreads();
  #pragma unroll
  for (int nt = 0; nt < 7; ++nt){
    int col = nt*16 + m;
    if (col < 100){
      #pragma unroll
      for (int rg = 0; rg < 4; ++rg){
        int rowl = q*4 + rg;
        float mean = fmaxf(acc[nt][rg], 0.f);
        float sd = sdb[rowl*100 + col];
        float e = jax_normal_at((uint32_t)(R0+rowl)*100u + (uint32_t)col);
        __builtin_nontemporal_store(mean, &o_mean[(size_t)(R0+rowl)*100 + col]);
        __builtin_nontemporal_store(fmaf(sd, e, mean), &o_state[(size_t)(R0+rowl)*100 + col]);
      }
    }
  }
  __syncthreads();
}

template<int WS>
__global__ void __launch_bounds__(256, 2) rssm_mfma(MainP p)
{
  __shared__ __align__(16) ushort_t lds[4 * 2 * SLAB];

  const int tid  = threadIdx.x;
  const int w    = tid >> 6;
  const int lane = tid & 63;
  const int q    = lane >> 4;
  const int m    = lane & 15;
  const int R0   = blockIdx.x * 64 + w * 16;

  ushort_t* bufX = lds + w * 2 * SLAB;
  ushort_t* bufH = bufX + SLAB;

  // ---- phase 1: stage [s*nt | a | 0] -> bufX (k 0..159); zero bufH pad cols
  for (int t = lane; t < 16*160; t += 64){
    int rr = t / 160, cc = t - rr*160;
    int grow = R0 + rr;
    float v = 0.f;
    if (cc < 100)      v = p.prev_state[(size_t)grow*100 + cc] * p.nonterm[grow];
    else if (cc < 132) v = p.prev_action[(size_t)grow*32 + (cc-100)];
    bufX[rr*STR + cc] = f2bf(v);
  }
  for (int t = lane; t < 16*24; t += 64){
    int rr = t / 24, cc = 200 + (t - rr*24);
    bufH[rr*STR + cc] = 0;
  }
  __syncthreads();

  // ---- phase 2: SA gemm -> h (relu) -> bufH
  {
    floatx4 acc[13];
    #pragma unroll
    for (int nt = 0; nt < 13; ++nt){
      int col = nt*16 + m;
      float bv = (col<200)? p.b_sa[col] : 0.f;
      acc[nt] = (floatx4){bv,bv,bv,bv};
    }
    #pragma unroll 1
    for (int kb = 0; kb < 5; ++kb){
      short8 a = afrag(bufX, m, kb, q);
      #pragma unroll
      for (int nt = 0; nt < 13; ++nt)
        acc[nt] = __builtin_amdgcn_mfma_f32_16x16x32_bf16(a, bfr<M_SA,WS>(p,kb,nt,lane,q,m), acc[nt], 0,0,0);
    }
    #pragma unroll
    for (int nt = 0; nt < 13; ++nt){
      int col = nt*16 + m;
      if (col < 200){
        #pragma unroll
        for (int rg = 0; rg < 4; ++rg)
          bufH[(q*4+rg)*STR + col] = f2bf(fmaxf(acc[nt][rg], 0.f));
      }
    }
  }

  // ---- phase 3: stage x = prev_belief -> bufX (zero pad to 223)
  for (int t = lane; t < 16*224; t += 64){
    int rr = t / 224, cc = t - rr*224;
    float v = 0.f;
    if (cc < 200)
      v = __builtin_nontemporal_load(&p.prev_belief[(size_t)(R0+rr)*200 + cc]);
    bufX[rr*STR + cc] = f2bf(v);
  }
  __syncthreads();

  // ---- phase 4: GRU (two column chunks; nb -> HBM store AND nbv registers)
  floatx4 nbv[13];
  gru_chunk<WS,7,0>(p, bufX, bufH, R0, m, q, lane, nbv);
  gru_chunk<WS,6,7>(p, bufX, bufH, R0, m, q, lane, nbv);

  // ---- stage nb -> bufX directly from registers (bf16). No HBM round-trip:
  // same fp32 value through the same RNE f2bf => bit-identical to the old
  // store->reload path. Pad cols 200..223 of bufX untouched since phase 3
  // (still zero). Slabs are per-wave, so no __syncthreads needed here.
  #pragma unroll
  for (int nt = 0; nt < 13; ++nt){
    int col = nt*16 + m;
    if (col < 200){
      #pragma unroll
      for (int rg = 0; rg < 4; ++rg)
        bufX[(q*4+rg)*STR + col] = f2bf(nbv[nt][rg]);
    }
  }

  // ---- phase 5: bp gemm -> hp -> bufH
  {
    floatx4 acc[13];
    #pragma unroll
    for (int nt = 0; nt < 13; ++nt){
      int col = nt*16 + m;
      float bv = (col<200)? p.b_bp[col] : 0.f;
      acc[nt] = (floatx4){bv,bv,bv,bv};
    }
    #pragma unroll 1
    for (int kb = 0; kb < 7; ++kb){
      short8 a = afrag(bufX, m, kb, q);
      #pragma unroll
      for (int nt = 0; nt < 13; ++nt)
        acc[nt] = __builtin_amdgcn_mfma_f32_16x16x32_bf16(a, bfr<M_BP,WS>(p,kb,nt,lane,q,m), acc[nt], 0,0,0);
    }
    #pragma unroll
    for (int nt = 0; nt < 13; ++nt){
      int col = nt*16 + m;
      if (col < 200){
        #pragma unroll
        for (int rg = 0; rg < 4; ++rg)
          bufH[(q*4+rg)*STR + col] = f2bf(fmaxf(acc[nt][rg], 0.f));
      }
    }
  }
  __syncthreads();

  // ---- phase 6: sp gemm -> prior outputs (fp32 scratch in bufH)
  {
    floatx4 acc[13];
    #pragma unroll
    for (int nt = 0; nt < 13; ++nt){
      int col = nt*16 + m;
      float bv = (col<200)? p.b_sp[col] : 0.f;
      acc[nt] = (floatx4){bv,bv,bv,bv};
    }
    #pragma unroll 1
    for (int kb = 0; kb < 7; ++kb){
      short8 a = afrag(bufH, m, kb, q);
      #pragma unroll
      for (int nt = 0; nt < 13; ++nt)
        acc[nt] = __builtin_amdgcn_mfma_f32_16x16x32_bf16(a, bfr<M_SP,WS>(p,kb,nt,lane,q,m), acc[nt], 0,0,0);
    }
    head_out(acc, (float*)bufH,
             p.out + (size_t)BATCH*200, p.out + (size_t)BATCH*300, p.out + (size_t)BATCH*400,
             R0, m, q);
  }

  // ---- phase 7: hq gemm (nb A-frags from bufX, obs streamed from HBM)
  {
    floatx4 acc[13];
    #pragma unroll
    for (int nt = 0; nt < 13; ++nt){
      int col = nt*16 + m;
      float bv = (col<200)? p.b_bq[col] : 0.f;
      acc[nt] = (floatx4){bv,bv,bv,bv};
    }
    #pragma unroll 1
    for (int kb = 0; kb < 7; ++kb){
      short8 a = afrag(bufX, m, kb, q);
      #pragma unroll
      for (int nt = 0; nt < 13; ++nt)
        acc[nt] = __builtin_amdgcn_mfma_f32_16x16x32_bf16(a, bfr<M_BQ,WS>(p,kb,nt,lane,q,m), acc[nt], 0,0,0);
    }
    const float* orow_base = p.observation + (size_t)(R0+m)*1024;
    #pragma unroll 1
    for (int kb = 7; kb < 39; ++kb){
      const float* orow = orow_base + (kb*32 - 224) + q*8;
      floatx4 o1 = __builtin_nontemporal_load((const floatx4*)(orow));
      floatx4 o2 = __builtin_nontemporal_load((const floatx4*)(orow + 4));
      short8 ao;
      ao[0] = (short)f2bf(o1[0]); ao[1] = (short)f2bf(o1[1]);
      ao[2] = (short)f2bf(o1[2]); ao[3] = (short)f2bf(o1[3]);
      ao[4] = (short)f2bf(o2[0]); ao[5] = (short)f2bf(o2[1]);
      ao[6] = (short)f2bf(o2[2]); ao[7] = (short)f2bf(o2[3]);
      #pragma unroll
      for (int nt = 0; nt < 13; ++nt)
        acc[nt] = __builtin_amdgcn_mfma_f32_16x16x32_bf16(ao, bfr<M_BQ,WS>(p,kb,nt,lane,q,m), acc[nt], 0,0,0);
    }
    // hq -> bufH + re-zero pad cols (phase-6 scratch clobbered them; avoids NaN A-pads)
    #pragma unroll
    for (int nt = 0; nt < 13; ++nt){
      int col = nt*16 + m;
      if (col < 200){
        #pragma unroll
        for (int rg = 0; rg < 4; ++rg)
          bufH[(q*4+rg)*STR + col] = f2bf(fmaxf(acc[nt][rg], 0.f));
      }
    }
    for (int t = lane; t < 16*24; t += 64){
      int rr = t / 24, cc = 200 + (t - rr*24);
      bufH[rr*STR + cc] = 0;
    }
  }
  __syncthreads();

  // ---- phase 8: sq gemm -> posterior outputs (same eps; fp32 scratch in bufX)
  {
    floatx4 acc[13];
    #pragma unroll
    for (int nt = 0; nt < 13; ++nt){
      int col = nt*16 + m;
      float bv = (col<200)? p.b_sq[col] : 0.f;
      acc[nt] = (floatx4){bv,bv,bv,bv};
    }
    #pragma unroll 1
    for (int kb = 0; kb < 7; ++kb){
      short8 a = afrag(bufH, m, kb, q);
      #pragma unroll
      for (int nt = 0; nt < 13; ++nt)
        acc[nt] = __builtin_amdgcn_mfma_f32_16x16x32_bf16(a, bfr<M_SQ,WS>(p,kb,nt,lane,q,m), acc[nt], 0,0,0);
    }
    head_out(acc, (float*)bufX,
             p.out + (size_t)BATCH*500, p.out + (size_t)BATCH*600, p.out + (size_t)BATCH*700,
             R0, m, q);
  }
}

extern "C" void kernel_launch(void* const* d_in, const int* in_sizes, int n_in,
                              void* d_out, int out_size, void* d_ws, size_t ws_size,
                              hipStream_t stream)
{
  MainP p;
  p.prev_state  = (const float*)d_in[0];
  p.prev_action = (const float*)d_in[1];
  p.prev_belief = (const float*)d_in[2];
  p.observation = (const float*)d_in[3];
  p.nonterm     = (const float*)d_in[4];
  p.b_sa = (const float*)d_in[6];
  p.b_ir = (const float*)d_in[8];
  p.b_iz = (const float*)d_in[10];
  p.b_in = (const float*)d_in[12];
  p.b_hn = (const float*)d_in[16];
  p.b_bp = (const float*)d_in[18];
  p.b_sp = (const float*)d_in[20];
  p.b_bq = (const float*)d_in[22];
  p.b_sq = (const float*)d_in[24];
  p.W[M_SA] = (const float*)d_in[5];
  p.W[M_IR] = (const float*)d_in[7];
  p.W[M_HR] = (const float*)d_in[13];
  p.W[M_IZ] = (const float*)d_in[9];
  p.W[M_HZ] = (const float*)d_in[14];
  p.W[M_IN] = (const float*)d_in[11];
  p.W[M_HN] = (const float*)d_in[15];
  p.W[M_BP] = (const float*)d_in[17];
  p.W[M_SP] = (const float*)d_in[19];
  p.W[M_SQ] = (const float*)d_in[23];
  p.W[M_BQ] = (const float*)d_in[21];
  p.ws   = (const ushort_t*)d_ws;
  p.out  = (float*)d_out;

  bool use_ws = (ws_size >= (size_t)TOT_TILES * 1024u);
  if (use_ws){
    ConvP cp;
    cp.src[0]  = p.W[M_SA]; cp.src[1]  = p.W[M_IR]; cp.src[2]  = p.W[M_HR];
    cp.src[3]  = p.W[M_IZ]; cp.src[4]  = p.W[M_HZ]; cp.src[5]  = p.W[M_IN];
    cp.src[6]  = p.W[M_HN]; cp.src[7]  = p.W[M_BP]; cp.src[8]  = p.W[M_SP];
    cp.src[9]  = p.W[M_SQ]; cp.src[10] = p.W[M_BQ];
    cp.dst     = (ushort_t*)d_ws;
    convw<<<TOT_TILES, 64, 0, stream>>>(cp);
    rssm_mfma<1><<<512, 256, 0, stream>>>(p);
  } else {
    rssm_mfma<0><<<512, 256, 0, stream>>>(p);
  }
}

// Round 4
// 525.489 us; speedup vs baseline: 1.5496x; 1.5496x over previous
//
#include <hip/hip_runtime.h>
#include <stdint.h>

typedef short short8 __attribute__((ext_vector_type(8)));
typedef float floatx4 __attribute__((ext_vector_type(4)));
typedef unsigned short ushort_t;

#define BATCH 32768
#define STR   232          // LDS row stride in bf16 elems (16 rows per wave slab)
#define SLAB  (16*STR)     // 3712 ushorts = 7424 B per buffer
#define TOT_TILES 1391     // ws need = TOT_TILES * 1024 B = 1.42 MB

// matrix ids (order matches convw src[] and TILE0)
#define M_SA 0
#define M_IR 1
#define M_HR 2
#define M_IZ 3
#define M_HZ 4
#define M_IN 5
#define M_HN 6
#define M_BP 7
#define M_SP 8
#define M_SQ 9
#define M_BQ 10

__device__ constexpr int TILE0[11] = {0,65,156,247,338,429,520,611,702,793,884};
__device__ constexpr int KLIM[11]  = {132,200,200,200,200,200,200,200,200,200,0};

__device__ __forceinline__ ushort_t f2bf(float f){
  uint32_t u = __float_as_uint(f);
  uint32_t r = (u + 0x7fffu + ((u >> 16) & 1u)) >> 16;   // RNE
  return (ushort_t)r;
}
__device__ __forceinline__ float bf2f(ushort_t h){ return __uint_as_float(((uint32_t)h) << 16); }

__device__ __forceinline__ float sigmf_(float x){ return 1.f / (1.f + expf(-x)); }
__device__ __forceinline__ float softplusf_(float x){
  return fmaxf(x, 0.f) + log1pf(expf(-fabsf(x)));
}
__device__ __forceinline__ uint32_t rotl32(uint32_t x, int r){ return (x << r) | (x >> (32 - r)); }

__device__ __forceinline__ void threefry2x32_k42(uint32_t x0, uint32_t x1,
                                                 uint32_t& o0, uint32_t& o1){
  const uint32_t k0 = 0u, k1 = 42u, k2 = 0u ^ 42u ^ 0x1BD11BDAu;
  x0 += k0; x1 += k1;
#define TF_R(rot) { x0 += x1; x1 = rotl32(x1, rot); x1 ^= x0; }
  TF_R(13) TF_R(15) TF_R(26) TF_R(6)  x0 += k1; x1 += k2 + 1u;
  TF_R(17) TF_R(29) TF_R(16) TF_R(24) x0 += k2; x1 += k0 + 2u;
  TF_R(13) TF_R(15) TF_R(26) TF_R(6)  x0 += k0; x1 += k1 + 3u;
  TF_R(17) TF_R(29) TF_R(16) TF_R(24) x0 += k1; x1 += k2 + 4u;
  TF_R(13) TF_R(15) TF_R(26) TF_R(6)  x0 += k2; x1 += k0 + 5u;
#undef TF_R
  o0 = x0; o1 = x1;
}

__device__ __forceinline__ float jax_erfinv(float x){
  float w = -log1pf(-x * x);
  float p;
  if (w < 5.0f) {
    w -= 2.5f;
    p = 2.81022636e-08f;
    p = fmaf(p, w, 3.43273939e-07f);
    p = fmaf(p, w, -3.5233877e-06f);
    p = fmaf(p, w, -4.39150654e-06f);
    p = fmaf(p, w, 0.00021858087f);
    p = fmaf(p, w, -0.00125372503f);
    p = fmaf(p, w, -0.00417768164f);
    p = fmaf(p, w, 0.246640727f);
    p = fmaf(p, w, 1.50140941f);
  } else {
    w = sqrtf(w) - 3.0f;
    p = -0.000200214257f;
    p = fmaf(p, w, 0.000100950558f);
    p = fmaf(p, w, 0.00134934322f);
    p = fmaf(p, w, -0.00367342844f);
    p = fmaf(p, w, 0.00573950773f);
    p = fmaf(p, w, -0.0076224613f);
    p = fmaf(p, w, 0.00943887047f);
    p = fmaf(p, w, 1.00167406f);
    p = fmaf(p, w, 2.83297682f);
  }
  return p * x;
}

// partitionable threefry: counter=(0,j), bits = o0^o1  (verified passing)
__device__ __forceinline__ float jax_normal_at(uint32_t j){
  uint32_t o0, o1;
  threefry2x32_k42(0u, j, o0, o1);
  uint32_t bits = o0 ^ o1;
  const float lo = -0.99999994f;
  float f = __uint_as_float((bits >> 9) | 0x3f800000u) - 1.0f;
  float fm = f * 1.99999994f;
  float u = fmaxf(lo, fm + lo);
  return 1.41421356f * jax_erfinv(u);
}

// ---------------- weight conversion kernel (ws path only) ----------------
struct ConvP { const float* src[11]; ushort_t* dst; };

__global__ void __launch_bounds__(64) convw(ConvP cp)
{
  int t = blockIdx.x;
  int lane = threadIdx.x;
  const int cum[12] = {0,65,156,247,338,429,520,611,702,793,884,1391};
  int mi = 0;
  #pragma unroll
  for (int i = 0; i < 11; ++i) if (t >= cum[i+1]) mi = i+1;
  int lt = t - cum[mi];
  int kb = lt / 13, nt = lt - kb*13;
  const float* S = cp.src[mi];
  int q = lane >> 4, m = lane & 15;
  int n = nt*16 + m;
  ushort_t* D = cp.dst + (size_t)t*512 + lane*8;
  #pragma unroll
  for (int j = 0; j < 8; ++j){
    int k = kb*32 + q*8 + j;
    float v = 0.f;
    if (n < 200){
      if (mi == 10){                       // W_bq: k<200 nb rows; 200..223 zero; >=224 obs rows
        if (k < 200) v = S[k*200+n];
        else if (k >= 224) v = S[(size_t)(k-24)*200+n];
      } else {
        int K = (mi == 0) ? 132 : 200;
        if (k < K) v = S[k*200+n];
      }
    }
    D[j] = f2bf(v);
  }
}

// ---------------- main fused kernel ----------------
struct MainP {
  const float* prev_state; const float* prev_action; const float* prev_belief;
  const float* observation; const float* nonterm;
  const float* b_sa; const float* b_ir; const float* b_iz; const float* b_in; const float* b_hn;
  const float* b_bp; const float* b_sp; const float* b_bq; const float* b_sq;
  const float* W[11];          // fp32 weights by mat id (direct path)
  const ushort_t* ws;
  float* out;
};

__device__ __forceinline__ short8 afrag(const ushort_t* buf, int m, int kb, int q){
  return *(const short8*)(buf + m*STR + kb*32 + q*8);
}

// ================= staged-pipeline machinery (WS path) =================
// Static schedule of 214 stage-steps; each step copies cnt (7 or 6) contiguous
// 1KB tiles from ws into one of two 7-tile LDS buffers. Order EXACTLY matches
// consume order below.
#define NSTEPS 214
#define STAGE_US 3584   // 7 tiles * 512 ushorts

struct Sched {
  short t0[NSTEPS]; signed char cnt[NSTEPS];
  constexpr Sched() : t0(), cnt() {
    int s = 0;
    // P2: SA, kb 0..4, halves (7+6)
    for (int kb = 0; kb < 5; ++kb){
      t0[s] = (short)(0 + kb*13);     cnt[s] = 7; ++s;
      t0[s] = (short)(0 + kb*13 + 7); cnt[s] = 6; ++s;
    }
    // GRU chunk1 (nt 0..6): kb 0..6 x mats IR,HR,IZ,HZ,IN,HN (ids 1..6, T0=65+91*(mt-1))
    for (int kb = 0; kb < 7; ++kb)
      for (int mt = 1; mt <= 6; ++mt){ t0[s] = (short)(65 + 91*(mt-1) + kb*13);     cnt[s] = 7; ++s; }
    // GRU chunk2 (nt 7..12)
    for (int kb = 0; kb < 7; ++kb)
      for (int mt = 1; mt <= 6; ++mt){ t0[s] = (short)(65 + 91*(mt-1) + kb*13 + 7); cnt[s] = 6; ++s; }
    // P5: BP (T0=611), kb 0..6
    for (int kb = 0; kb < 7; ++kb){
      t0[s] = (short)(611 + kb*13);     cnt[s] = 7; ++s;
      t0[s] = (short)(611 + kb*13 + 7); cnt[s] = 6; ++s;
    }
    // P6: SP (T0=702), kb 0..6
    for (int kb = 0; kb < 7; ++kb){
      t0[s] = (short)(702 + kb*13);     cnt[s] = 7; ++s;
      t0[s] = (short)(702 + kb*13 + 7); cnt[s] = 6; ++s;
    }
    // P7: BQ (T0=884), kb 0..38
    for (int kb = 0; kb < 39; ++kb){
      t0[s] = (short)(884 + kb*13);     cnt[s] = 7; ++s;
      t0[s] = (short)(884 + kb*13 + 7); cnt[s] = 6; ++s;
    }
    // P8: SQ (T0=793), kb 0..6
    for (int kb = 0; kb < 7; ++kb){
      t0[s] = (short)(793 + kb*13);     cnt[s] = 7; ++s;
      t0[s] = (short)(793 + kb*13 + 7); cnt[s] = 6; ++s;
    }
  }
};
__device__ constexpr Sched SCHED{};

// issue global_load_lds copies for one stage step (no wait; drained at the
// step-end __syncthreads). Wave w handles tiles w, w+4. 16B/lane x 64 = 1KB/inst.
// LDS dest is wave-uniform base (HW writes base + lane*16); global src is per-lane.
__device__ __forceinline__ void stage_issue(const ushort_t* ws, ushort_t* sbuf,
                                            int step, int w, int lane)
{
  if (step >= NSTEPS) return;
  const int t0 = SCHED.t0[step];
  const int cn = SCHED.cnt[step];
  ushort_t* dstb = sbuf + (step & 1) * STAGE_US;
  const ushort_t* srcb = ws + ((size_t)t0 << 9) + (lane << 3);
  #pragma unroll
  for (int r = 0; r < 2; ++r){
    int tt = w + r*4;
    if (tt < cn){
      __builtin_amdgcn_global_load_lds(
        (const __attribute__((address_space(1))) uint32_t*)(const void*)(srcb + (tt << 9)),
        (__attribute__((address_space(3)))       uint32_t*)(void*)(dstb + (tt << 9)),
        16, 0, 0);
    }
  }
}

// read one B-fragment (tile j of current step) from the stage buffer
__device__ __forceinline__ short8 sfrag(const ushort_t* sbuf, int step, int j, int lane){
  return *(const short8*)(sbuf + (step & 1) * STAGE_US + (j << 9) + (lane << 3));
}

// one kb of a 13-column-tile GEMM phase = 2 stage-steps
__device__ __forceinline__ void gemm13_kb(const MainP& p, ushort_t* stageb, int& sidx,
    const ushort_t* asrc, floatx4 (&acc)[13], int kb, int m, int q, int lane, int w)
{
  short8 a = afrag(asrc, m, kb, q);
  stage_issue(p.ws, stageb, sidx+1, w, lane);
  #pragma unroll
  for (int j = 0; j < 7; ++j)
    acc[j] = __builtin_amdgcn_mfma_f32_16x16x32_bf16(a, sfrag(stageb, sidx, j, lane), acc[j], 0,0,0);
  __syncthreads(); ++sidx;
  stage_issue(p.ws, stageb, sidx+1, w, lane);
  #pragma unroll
  for (int j = 0; j < 6; ++j)
    acc[7+j] = __builtin_amdgcn_mfma_f32_16x16x32_bf16(a, sfrag(stageb, sidx, j, lane), acc[7+j], 0,0,0);
  __syncthreads(); ++sidx;
}

// GRU column-chunk, staged: per kb, 6 stage-steps (IR,HR,IZ,HZ,IN,HN).
// Per-element accumulation order identical to the verified direct version.
template<int CNT, int NT0>
__device__ __forceinline__ void gru_chunk_staged(const MainP& p, ushort_t* stageb, int& sidx,
    const ushort_t* bufX, const ushort_t* bufH, int R0, int m, int q, int lane, int w,
    floatx4 (&nbv)[13])
{
  floatx4 aR[CNT], aZ[CNT], aXN[CNT], aHN[CNT];
  #pragma unroll
  for (int i = 0; i < CNT; ++i){
    int col = (NT0+i)*16 + m;
    float br = (col<200)? p.b_ir[col] : 0.f;
    float bz = (col<200)? p.b_iz[col] : 0.f;
    float bn = (col<200)? p.b_in[col] : 0.f;
    float bh = (col<200)? p.b_hn[col] : 0.f;
    aR[i]  = (floatx4){br,br,br,br};
    aZ[i]  = (floatx4){bz,bz,bz,bz};
    aXN[i] = (floatx4){bn,bn,bn,bn};
    aHN[i] = (floatx4){bh,bh,bh,bh};
  }
#define GRU_STEP(AV, ACC) \
  stage_issue(p.ws, stageb, sidx+1, w, lane); \
  _Pragma("unroll") \
  for (int i = 0; i < CNT; ++i) \
    ACC[i] = __builtin_amdgcn_mfma_f32_16x16x32_bf16(AV, sfrag(stageb, sidx, i, lane), ACC[i], 0,0,0); \
  __syncthreads(); ++sidx;

  #pragma unroll 1
  for (int kb = 0; kb < 7; ++kb){
    short8 ax = afrag(bufX, m, kb, q);
    short8 ah = afrag(bufH, m, kb, q);
    GRU_STEP(ax, aR)   // IR
    GRU_STEP(ah, aR)   // HR
    GRU_STEP(ax, aZ)   // IZ
    GRU_STEP(ah, aZ)   // HZ
    GRU_STEP(ax, aXN)  // IN
    GRU_STEP(ah, aHN)  // HN
  }
#undef GRU_STEP
  #pragma unroll
  for (int i = 0; i < CNT; ++i){
    int col = (NT0+i)*16 + m;
    if (col < 200){
      #pragma unroll
      for (int rg = 0; rg < 4; ++rg){
        int rowl = q*4 + rg;
        float rr = sigmf_(aR[i][rg]);
        float zz = sigmf_(aZ[i][rg]);
        float nn = tanhf(fmaf(rr, aHN[i][rg], aXN[i][rg]));
        float hv = bf2f(bufH[rowl*STR + col]);
        float nb = fmaf(zz, hv - nn, nn);
        nbv[NT0+i][rg] = nb;
        __builtin_nontemporal_store(nb, &p.out[(size_t)(R0+rowl)*200 + col]);
      }
    }
  }
}

// head epilogue (verified): std transposed via fp32 LDS scratch
__device__ __forceinline__ void head_out(const floatx4* acc, float* sdb,
    float* o_state, float* o_mean, float* o_std, int R0, int m, int q)
{
  #pragma unroll
  for (int nt = 6; nt < 13; ++nt){
    int col = nt*16 + m;
    if (col >= 100 && col < 200){
      #pragma unroll
      for (int rg = 0; rg < 4; ++rg){
        int rowl = q*4 + rg;
        float sr = fmaxf(acc[nt][rg], 0.f);
        float sd = softplusf_(sr) + 0.1f;
        sdb[rowl*100 + (col-100)] = sd;
        __builtin_nontemporal_store(sd, &o_std[(size_t)(R0+rowl)*100 + (col-100)]);
      }
    }
  }
  __syncthreads();
  #pragma unroll
  for (int nt = 0; nt < 7; ++nt){
    int col = nt*16 + m;
    if (col < 100){
      #pragma unroll
      for (int rg = 0; rg < 4; ++rg){
        int rowl = q*4 + rg;
        float mean = fmaxf(acc[nt][rg], 0.f);
        float sd = sdb[rowl*100 + col];
        float e = jax_normal_at((uint32_t)(R0+rowl)*100u + (uint32_t)col);
        __builtin_nontemporal_store(mean, &o_mean[(size_t)(R0+rowl)*100 + col]);
        __builtin_nontemporal_store(fmaf(sd, e, mean), &o_state[(size_t)(R0+rowl)*100 + col]);
      }
    }
  }
  __syncthreads();
}

// =================== staged kernel (ws path) ===================
__global__ void __launch_bounds__(256, 2) rssm_staged(MainP p)
{
  __shared__ __align__(16) ushort_t lds[8*SLAB + 2*STAGE_US];  // 73728 B -> 2 blocks/CU

  const int tid  = threadIdx.x;
  const int w    = tid >> 6;
  const int lane = tid & 63;
  const int q    = lane >> 4;
  const int m    = lane & 15;
  const int R0   = blockIdx.x * 64 + w * 16;

  ushort_t* bufX   = lds + w * 2 * SLAB;
  ushort_t* bufH   = bufX + SLAB;
  ushort_t* stageb = lds + 8*SLAB;
  int sidx = 0;

  // prologue: stage step 0 (drained+synced by phase-1's __syncthreads)
  stage_issue(p.ws, stageb, 0, w, lane);

  // ---- phase 1: stage [s*nt | a | 0] -> bufX (k 0..159); zero bufH pad cols
  for (int t = lane; t < 16*160; t += 64){
    int rr = t / 160, cc = t - rr*160;
    int grow = R0 + rr;
    float v = 0.f;
    if (cc < 100)      v = p.prev_state[(size_t)grow*100 + cc] * p.nonterm[grow];
    else if (cc < 132) v = p.prev_action[(size_t)grow*32 + (cc-100)];
    bufX[rr*STR + cc] = f2bf(v);
  }
  for (int t = lane; t < 16*24; t += 64){
    int rr = t / 24, cc = 200 + (t - rr*24);
    bufH[rr*STR + cc] = 0;
  }
  __syncthreads();

  // ---- phase 2: SA gemm -> h (relu) -> bufH   (steps 0..9)
  {
    floatx4 acc[13];
    #pragma unroll
    for (int nt = 0; nt < 13; ++nt){
      int col = nt*16 + m;
      float bv = (col<200)? p.b_sa[col] : 0.f;
      acc[nt] = (floatx4){bv,bv,bv,bv};
    }
    #pragma unroll 1
    for (int kb = 0; kb < 5; ++kb)
      gemm13_kb(p, stageb, sidx, bufX, acc, kb, m, q, lane, w);
    #pragma unroll
    for (int nt = 0; nt < 13; ++nt){
      int col = nt*16 + m;
      if (col < 200){
        #pragma unroll
        for (int rg = 0; rg < 4; ++rg)
          bufH[(q*4+rg)*STR + col] = f2bf(fmaxf(acc[nt][rg], 0.f));
      }
    }
  }

  // ---- phase 3: stage x = prev_belief -> bufX (zero pad to 223)
  for (int t = lane; t < 16*224; t += 64){
    int rr = t / 224, cc = t - rr*224;
    float v = 0.f;
    if (cc < 200)
      v = __builtin_nontemporal_load(&p.prev_belief[(size_t)(R0+rr)*200 + cc]);
    bufX[rr*STR + cc] = f2bf(v);
  }
  __syncthreads();

  // ---- phase 4: GRU (two column chunks; nb -> HBM store AND nbv registers)
  // steps 10..51 (chunk1), 52..93 (chunk2)
  floatx4 nbv[13];
  gru_chunk_staged<7,0>(p, stageb, sidx, bufX, bufH, R0, m, q, lane, w, nbv);
  gru_chunk_staged<6,7>(p, stageb, sidx, bufX, bufH, R0, m, q, lane, w, nbv);

  // ---- stage nb -> bufX directly from registers (bf16); pads still zero
  #pragma unroll
  for (int nt = 0; nt < 13; ++nt){
    int col = nt*16 + m;
    if (col < 200){
      #pragma unroll
      for (int rg = 0; rg < 4; ++rg)
        bufX[(q*4+rg)*STR + col] = f2bf(nbv[nt][rg]);
    }
  }

  // ---- phase 5: bp gemm -> hp -> bufH   (steps 94..107)
  {
    floatx4 acc[13];
    #pragma unroll
    for (int nt = 0; nt < 13; ++nt){
      int col = nt*16 + m;
      float bv = (col<200)? p.b_bp[col] : 0.f;
      acc[nt] = (floatx4){bv,bv,bv,bv};
    }
    #pragma unroll 1
    for (int kb = 0; kb < 7; ++kb)
      gemm13_kb(p, stageb, sidx, bufX, acc, kb, m, q, lane, w);
    #pragma unroll
    for (int nt = 0; nt < 13; ++nt){
      int col = nt*16 + m;
      if (col < 200){
        #pragma unroll
        for (int rg = 0; rg < 4; ++rg)
          bufH[(q*4+rg)*STR + col] = f2bf(fmaxf(acc[nt][rg], 0.f));
      }
    }
  }
  __syncthreads();

  // ---- phase 6: sp gemm -> prior outputs (fp32 scratch in bufH)  (steps 108..121)
  {
    floatx4 acc[13];
    #pragma unroll
    for (int nt = 0; nt < 13; ++nt){
      int col = nt*16 + m;
      float bv = (col<200)? p.b_sp[col] : 0.f;
      acc[nt] = (floatx4){bv,bv,bv,bv};
    }
    #pragma unroll 1
    for (int kb = 0; kb < 7; ++kb)
      gemm13_kb(p, stageb, sidx, bufH, acc, kb, m, q, lane, w);
    head_out(acc, (float*)bufH,
             p.out + (size_t)BATCH*200, p.out + (size_t)BATCH*300, p.out + (size_t)BATCH*400,
             R0, m, q);
  }

  // ---- phase 7: hq gemm (nb A-frags from bufX, obs streamed from HBM)  (steps 122..199)
  {
    floatx4 acc[13];
    #pragma unroll
    for (int nt = 0; nt < 13; ++nt){
      int col = nt*16 + m;
      float bv = (col<200)? p.b_bq[col] : 0.f;
      acc[nt] = (floatx4){bv,bv,bv,bv};
    }
    #pragma unroll 1
    for (int kb = 0; kb < 7; ++kb)
      gemm13_kb(p, stageb, sidx, bufX, acc, kb, m, q, lane, w);

    const float* orow_base = p.observation + (size_t)(R0+m)*1024;
    floatx4 o1 = __builtin_nontemporal_load((const floatx4*)(orow_base + 0 + q*8));
    floatx4 o2 = __builtin_nontemporal_load((const floatx4*)(orow_base + 0 + q*8 + 4));
    #pragma unroll 1
    for (int kb = 7; kb < 39; ++kb){
      floatx4 n1 = {0,0,0,0}, n2 = {0,0,0,0};
      if (kb < 38){
        const float* nr = orow_base + ((kb+1)*32 - 224) + q*8;
        n1 = __builtin_nontemporal_load((const floatx4*)(nr));
        n2 = __builtin_nontemporal_load((const floatx4*)(nr + 4));
      }
      short8 ao;
      ao[0] = (short)f2bf(o1[0]); ao[1] = (short)f2bf(o1[1]);
      ao[2] = (short)f2bf(o1[2]); ao[3] = (short)f2bf(o1[3]);
      ao[4] = (short)f2bf(o2[0]); ao[5] = (short)f2bf(o2[1]);
      ao[6] = (short)f2bf(o2[2]); ao[7] = (short)f2bf(o2[3]);
      stage_issue(p.ws, stageb, sidx+1, w, lane);
      #pragma unroll
      for (int j = 0; j < 7; ++j)
        acc[j] = __builtin_amdgcn_mfma_f32_16x16x32_bf16(ao, sfrag(stageb, sidx, j, lane), acc[j], 0,0,0);
      __syncthreads(); ++sidx;
      stage_issue(p.ws, stageb, sidx+1, w, lane);
      #pragma unroll
      for (int j = 0; j < 6; ++j)
        acc[7+j] = __builtin_amdgcn_mfma_f32_16x16x32_bf16(ao, sfrag(stageb, sidx, j, lane), acc[7+j], 0,0,0);
      __syncthreads(); ++sidx;
      o1 = n1; o2 = n2;
    }
    // hq -> bufH + re-zero pad cols (phase-6 scratch clobbered them)
    #pragma unroll
    for (int nt = 0; nt < 13; ++nt){
      int col = nt*16 + m;
      if (col < 200){
        #pragma unroll
        for (int rg = 0; rg < 4; ++rg)
          bufH[(q*4+rg)*STR + col] = f2bf(fmaxf(acc[nt][rg], 0.f));
      }
    }
    for (int t = lane; t < 16*24; t += 64){
      int rr = t / 24, cc = 200 + (t - rr*24);
      bufH[rr*STR + cc] = 0;
    }
  }
  __syncthreads();

  // ---- phase 8: sq gemm -> posterior outputs (fp32 scratch in bufX)  (steps 200..213)
  {
    floatx4 acc[13];
    #pragma unroll
    for (int nt = 0; nt < 13; ++nt){
      int col = nt*16 + m;
      float bv = (col<200)? p.b_sq[col] : 0.f;
      acc[nt] = (floatx4){bv,bv,bv,bv};
    }
    #pragma unroll 1
    for (int kb = 0; kb < 7; ++kb)
      gemm13_kb(p, stageb, sidx, bufH, acc, kb, m, q, lane, w);
    head_out(acc, (float*)bufX,
             p.out + (size_t)BATCH*500, p.out + (size_t)BATCH*600, p.out + (size_t)BATCH*700,
             R0, m, q);
  }
}

// =================== direct fallback (no ws) — verified path ===================
template<int MAT>
__device__ __forceinline__ short8 bfr0(const MainP& p, int kb, int nt, int lane, int q, int m){
  int n = nt*16 + m;
  const float* S = p.W[MAT];
  uint32_t u[8];
  #pragma unroll
  for (int j = 0; j < 8; ++j){
    int k = kb*32 + q*8 + j;
    int srow;
    if (MAT == M_BQ) srow = (k < 200) ? k : ((k >= 224) ? k - 24 : -1);
    else             srow = (k < KLIM[MAT]) ? k : -1;
    float v = (srow >= 0 && n < 200) ? S[(size_t)srow*200 + n] : 0.f;
    u[j] = __float_as_uint(v);
  }
  short8 r;
  #pragma unroll
  for (int j = 0; j < 8; ++j) r[j] = (short)(u[j] >> 16);
  return r;
}

template<int CNT, int NT0>
__device__ __forceinline__ void gru_chunk0(const MainP& p,
    const ushort_t* bufX, const ushort_t* bufH, int R0, int m, int q, int lane,
    floatx4 (&nbv)[13])
{
  floatx4 aR[CNT], aZ[CNT], aXN[CNT], aHN[CNT];
  #pragma unroll
  for (int i = 0; i < CNT; ++i){
    int col = (NT0+i)*16 + m;
    float br = (col<200)? p.b_ir[col] : 0.f;
    float bz = (col<200)? p.b_iz[col] : 0.f;
    float bn = (col<200)? p.b_in[col] : 0.f;
    float bh = (col<200)? p.b_hn[col] : 0.f;
    aR[i]  = (floatx4){br,br,br,br};
    aZ[i]  = (floatx4){bz,bz,bz,bz};
    aXN[i] = (floatx4){bn,bn,bn,bn};
    aHN[i] = (floatx4){bh,bh,bh,bh};
  }
  #pragma unroll 1
  for (int kb = 0; kb < 7; ++kb){
    short8 ax = afrag(bufX, m, kb, q);
    short8 ah = afrag(bufH, m, kb, q);
    #pragma unroll
    for (int i = 0; i < CNT; ++i){
      int nt = NT0 + i;
      aR[i]  = __builtin_amdgcn_mfma_f32_16x16x32_bf16(ax, bfr0<M_IR>(p,kb,nt,lane,q,m), aR[i], 0,0,0);
      aR[i]  = __builtin_amdgcn_mfma_f32_16x16x32_bf16(ah, bfr0<M_HR>(p,kb,nt,lane,q,m), aR[i], 0,0,0);
      aZ[i]  = __builtin_amdgcn_mfma_f32_16x16x32_bf16(ax, bfr0<M_IZ>(p,kb,nt,lane,q,m), aZ[i], 0,0,0);
      aZ[i]  = __builtin_amdgcn_mfma_f32_16x16x32_bf16(ah, bfr0<M_HZ>(p,kb,nt,lane,q,m), aZ[i], 0,0,0);
      aXN[i] = __builtin_amdgcn_mfma_f32_16x16x32_bf16(ax, bfr0<M_IN>(p,kb,nt,lane,q,m), aXN[i], 0,0,0);
      aHN[i] = __builtin_amdgcn_mfma_f32_16x16x32_bf16(ah, bfr0<M_HN>(p,kb,nt,lane,q,m), aHN[i], 0,0,0);
    }
  }
  #pragma unroll
  for (int i = 0; i < CNT; ++i){
    int col = (NT0+i)*16 + m;
    if (col < 200){
      #pragma unroll
      for (int rg = 0; rg < 4; ++rg){
        int rowl = q*4 + rg;
        float rr = sigmf_(aR[i][rg]);
        float zz = sigmf_(aZ[i][rg]);
        float nn = tanhf(fmaf(rr, aHN[i][rg], aXN[i][rg]));
        float hv = bf2f(bufH[rowl*STR + col]);
        float nb = fmaf(zz, hv - nn, nn);
        nbv[NT0+i][rg] = nb;
        __builtin_nontemporal_store(nb, &p.out[(size_t)(R0+rowl)*200 + col]);
      }
    }
  }
}

__global__ void __launch_bounds__(256, 2) rssm_direct(MainP p)
{
  __shared__ __align__(16) ushort_t lds[4 * 2 * SLAB];

  const int tid  = threadIdx.x;
  const int w    = tid >> 6;
  const int lane = tid & 63;
  const int q    = lane >> 4;
  const int m    = lane & 15;
  const int R0   = blockIdx.x * 64 + w * 16;

  ushort_t* bufX = lds + w * 2 * SLAB;
  ushort_t* bufH = bufX + SLAB;

  for (int t = lane; t < 16*160; t += 64){
    int rr = t / 160, cc = t - rr*160;
    int grow = R0 + rr;
    float v = 0.f;
    if (cc < 100)      v = p.prev_state[(size_t)grow*100 + cc] * p.nonterm[grow];
    else if (cc < 132) v = p.prev_action[(size_t)grow*32 + (cc-100)];
    bufX[rr*STR + cc] = f2bf(v);
  }
  for (int t = lane; t < 16*24; t += 64){
    int rr = t / 24, cc = 200 + (t - rr*24);
    bufH[rr*STR + cc] = 0;
  }
  __syncthreads();

  {
    floatx4 acc[13];
    #pragma unroll
    for (int nt = 0; nt < 13; ++nt){
      int col = nt*16 + m;
      float bv = (col<200)? p.b_sa[col] : 0.f;
      acc[nt] = (floatx4){bv,bv,bv,bv};
    }
    #pragma unroll 1
    for (int kb = 0; kb < 5; ++kb){
      short8 a = afrag(bufX, m, kb, q);
      #pragma unroll
      for (int nt = 0; nt < 13; ++nt)
        acc[nt] = __builtin_amdgcn_mfma_f32_16x16x32_bf16(a, bfr0<M_SA>(p,kb,nt,lane,q,m), acc[nt], 0,0,0);
    }
    #pragma unroll
    for (int nt = 0; nt < 13; ++nt){
      int col = nt*16 + m;
      if (col < 200){
        #pragma unroll
        for (int rg = 0; rg < 4; ++rg)
          bufH[(q*4+rg)*STR + col] = f2bf(fmaxf(acc[nt][rg], 0.f));
      }
    }
  }

  for (int t = lane; t < 16*224; t += 64){
    int rr = t / 224, cc = t - rr*224;
    float v = 0.f;
    if (cc < 200)
      v = __builtin_nontemporal_load(&p.prev_belief[(size_t)(R0+rr)*200 + cc]);
    bufX[rr*STR + cc] = f2bf(v);
  }
  __syncthreads();

  floatx4 nbv[13];
  gru_chunk0<7,0>(p, bufX, bufH, R0, m, q, lane, nbv);
  gru_chunk0<6,7>(p, bufX, bufH, R0, m, q, lane, nbv);

  #pragma unroll
  for (int nt = 0; nt < 13; ++nt){
    int col = nt*16 + m;
    if (col < 200){
      #pragma unroll
      for (int rg = 0; rg < 4; ++rg)
        bufX[(q*4+rg)*STR + col] = f2bf(nbv[nt][rg]);
    }
  }

  {
    floatx4 acc[13];
    #pragma unroll
    for (int nt = 0; nt < 13; ++nt){
      int col = nt*16 + m;
      float bv = (col<200)? p.b_bp[col] : 0.f;
      acc[nt] = (floatx4){bv,bv,bv,bv};
    }
    #pragma unroll 1
    for (int kb = 0; kb < 7; ++kb){
      short8 a = afrag(bufX, m, kb, q);
      #pragma unroll
      for (int nt = 0; nt < 13; ++nt)
        acc[nt] = __builtin_amdgcn_mfma_f32_16x16x32_bf16(a, bfr0<M_BP>(p,kb,nt,lane,q,m), acc[nt], 0,0,0);
    }
    #pragma unroll
    for (int nt = 0; nt < 13; ++nt){
      int col = nt*16 + m;
      if (col < 200){
        #pragma unroll
        for (int rg = 0; rg < 4; ++rg)
          bufH[(q*4+rg)*STR + col] = f2bf(fmaxf(acc[nt][rg], 0.f));
      }
    }
  }
  __syncthreads();

  {
    floatx4 acc[13];
    #pragma unroll
    for (int nt = 0; nt < 13; ++nt){
      int col = nt*16 + m;
      float bv = (col<200)? p.b_sp[col] : 0.f;
      acc[nt] = (floatx4){bv,bv,bv,bv};
    }
    #pragma unroll 1
    for (int kb = 0; kb < 7; ++kb){
      short8 a = afrag(bufH, m, kb, q);
      #pragma unroll
      for (int nt = 0; nt < 13; ++nt)
        acc[nt] = __builtin_amdgcn_mfma_f32_16x16x32_bf16(a, bfr0<M_SP>(p,kb,nt,lane,q,m), acc[nt], 0,0,0);
    }
    head_out(acc, (float*)bufH,
             p.out + (size_t)BATCH*200, p.out + (size_t)BATCH*300, p.out + (size_t)BATCH*400,
             R0, m, q);
  }

  {
    floatx4 acc[13];
    #pragma unroll
    for (int nt = 0; nt < 13; ++nt){
      int col = nt*16 + m;
      float bv = (col<200)? p.b_bq[col] : 0.f;
      acc[nt] = (floatx4){bv,bv,bv,bv};
    }
    #pragma unroll 1
    for (int kb = 0; kb < 7; ++kb){
      short8 a = afrag(bufX, m, kb, q);
      #pragma unroll
      for (int nt = 0; nt < 13; ++nt)
        acc[nt] = __builtin_amdgcn_mfma_f32_16x16x32_bf16(a, bfr0<M_BQ>(p,kb,nt,lane,q,m), acc[nt], 0,0,0);
    }
    const float* orow_base = p.observation + (size_t)(R0+m)*1024;
    #pragma unroll 1
    for (int kb = 7; kb < 39; ++kb){
      const float* orow = orow_base + (kb*32 - 224) + q*8;
      floatx4 o1 = __builtin_nontemporal_load((const floatx4*)(orow));
      floatx4 o2 = __builtin_nontemporal_load((const floatx4*)(orow + 4));
      short8 ao;
      ao[0] = (short)f2bf(o1[0]); ao[1] = (short)f2bf(o1[1]);
      ao[2] = (short)f2bf(o1[2]); ao[3] = (short)f2bf(o1[3]);
      ao[4] = (short)f2bf(o2[0]); ao[5] = (short)f2bf(o2[1]);
      ao[6] = (short)f2bf(o2[2]); ao[7] = (short)f2bf(o2[3]);
      #pragma unroll
      for (int nt = 0; nt < 13; ++nt)
        acc[nt] = __builtin_amdgcn_mfma_f32_16x16x32_bf16(ao, bfr0<M_BQ>(p,kb,nt,lane,q,m), acc[nt], 0,0,0);
    }
    #pragma unroll
    for (int nt = 0; nt < 13; ++nt){
      int col = nt*16 + m;
      if (col < 200){
        #pragma unroll
        for (int rg = 0; rg < 4; ++rg)
          bufH[(q*4+rg)*STR + col] = f2bf(fmaxf(acc[nt][rg], 0.f));
      }
    }
    for (int t = lane; t < 16*24; t += 64){
      int rr = t / 24, cc = 200 + (t - rr*24);
      bufH[rr*STR + cc] = 0;
    }
  }
  __syncthreads();

  {
    floatx4 acc[13];
    #pragma unroll
    for (int nt = 0; nt < 13; ++nt){
      int col = nt*16 + m;
      float bv = (col<200)? p.b_sq[col] : 0.f;
      acc[nt] = (floatx4){bv,bv,bv,bv};
    }
    #pragma unroll 1
    for (int kb = 0; kb < 7; ++kb){
      short8 a = afrag(bufH, m, kb, q);
      #pragma unroll
      for (int nt = 0; nt < 13; ++nt)
        acc[nt] = __builtin_amdgcn_mfma_f32_16x16x32_bf16(a, bfr0<M_SQ>(p,kb,nt,lane,q,m), acc[nt], 0,0,0);
    }
    head_out(acc, (float*)bufX,
             p.out + (size_t)BATCH*500, p.out + (size_t)BATCH*600, p.out + (size_t)BATCH*700,
             R0, m, q);
  }
}

extern "C" void kernel_launch(void* const* d_in, const int* in_sizes, int n_in,
                              void* d_out, int out_size, void* d_ws, size_t ws_size,
                              hipStream_t stream)
{
  MainP p;
  p.prev_state  = (const float*)d_in[0];
  p.prev_action = (const float*)d_in[1];
  p.prev_belief = (const float*)d_in[2];
  p.observation = (const float*)d_in[3];
  p.nonterm     = (const float*)d_in[4];
  p.b_sa = (const float*)d_in[6];
  p.b_ir = (const float*)d_in[8];
  p.b_iz = (const float*)d_in[10];
  p.b_in = (const float*)d_in[12];
  p.b_hn = (const float*)d_in[16];
  p.b_bp = (const float*)d_in[18];
  p.b_sp = (const float*)d_in[20];
  p.b_bq = (const float*)d_in[22];
  p.b_sq = (const float*)d_in[24];
  p.W[M_SA] = (const float*)d_in[5];
  p.W[M_IR] = (const float*)d_in[7];
  p.W[M_HR] = (const float*)d_in[13];
  p.W[M_IZ] = (const float*)d_in[9];
  p.W[M_HZ] = (const float*)d_in[14];
  p.W[M_IN] = (const float*)d_in[11];
  p.W[M_HN] = (const float*)d_in[15];
  p.W[M_BP] = (const float*)d_in[17];
  p.W[M_SP] = (const float*)d_in[19];
  p.W[M_SQ] = (const float*)d_in[23];
  p.W[M_BQ] = (const float*)d_in[21];
  p.ws   = (const ushort_t*)d_ws;
  p.out  = (float*)d_out;

  bool use_ws = (ws_size >= (size_t)TOT_TILES * 1024u);
  if (use_ws){
    ConvP cp;
    cp.src[0]  = p.W[M_SA]; cp.src[1]  = p.W[M_IR]; cp.src[2]  = p.W[M_HR];
    cp.src[3]  = p.W[M_IZ]; cp.src[4]  = p.W[M_HZ]; cp.src[5]  = p.W[M_IN];
    cp.src[6]  = p.W[M_HN]; cp.src[7]  = p.W[M_BP]; cp.src[8]  = p.W[M_SP];
    cp.src[9]  = p.W[M_SQ]; cp.src[10] = p.W[M_BQ];
    cp.dst     = (ushort_t*)d_ws;
    convw<<<TOT_TILES, 64, 0, stream>>>(cp);
    rssm_staged<<<512, 256, 0, stream>>>(p);
  } else {
    rssm_direct<<<512, 256, 0, stream>>>(p);
  }
}

// Round 5
// 513.918 us; speedup vs baseline: 1.5844x; 1.0225x over previous
//
#include <hip/hip_runtime.h>
#include <stdint.h>

typedef short short8 __attribute__((ext_vector_type(8)));
typedef float floatx4 __attribute__((ext_vector_type(4)));
typedef unsigned short ushort_t;

#define BATCH 32768
#define STR   232          // LDS row stride in bf16 elems (16 rows per wave slab; 464B = 16B-aligned rows)
#define SLAB  (16*STR)     // 3712 ushorts = 7424 B per buffer
#define TOT_TILES 1391     // ws need = TOT_TILES * 1024 B = 1.42 MB

// matrix ids (order matches convw src[] and TILE0)
#define M_SA 0
#define M_IR 1
#define M_HR 2
#define M_IZ 3
#define M_HZ 4
#define M_IN 5
#define M_HN 6
#define M_BP 7
#define M_SP 8
#define M_SQ 9
#define M_BQ 10

__device__ constexpr int TILE0[11] = {0,65,156,247,338,429,520,611,702,793,884};
__device__ constexpr int KLIM[11]  = {132,200,200,200,200,200,200,200,200,200,0};

__device__ __forceinline__ ushort_t f2bf(float f){
  uint32_t u = __float_as_uint(f);
  uint32_t r = (u + 0x7fffu + ((u >> 16) & 1u)) >> 16;   // RNE
  return (ushort_t)r;
}
__device__ __forceinline__ float bf2f(ushort_t h){ return __uint_as_float(((uint32_t)h) << 16); }

__device__ __forceinline__ float sigmf_(float x){ return 1.f / (1.f + expf(-x)); }
__device__ __forceinline__ float softplusf_(float x){
  return fmaxf(x, 0.f) + log1pf(expf(-fabsf(x)));
}
__device__ __forceinline__ uint32_t rotl32(uint32_t x, int r){ return (x << r) | (x >> (32 - r)); }

__device__ __forceinline__ void threefry2x32_k42(uint32_t x0, uint32_t x1,
                                                 uint32_t& o0, uint32_t& o1){
  const uint32_t k0 = 0u, k1 = 42u, k2 = 0u ^ 42u ^ 0x1BD11BDAu;
  x0 += k0; x1 += k1;
#define TF_R(rot) { x0 += x1; x1 = rotl32(x1, rot); x1 ^= x0; }
  TF_R(13) TF_R(15) TF_R(26) TF_R(6)  x0 += k1; x1 += k2 + 1u;
  TF_R(17) TF_R(29) TF_R(16) TF_R(24) x0 += k2; x1 += k0 + 2u;
  TF_R(13) TF_R(15) TF_R(26) TF_R(6)  x0 += k0; x1 += k1 + 3u;
  TF_R(17) TF_R(29) TF_R(16) TF_R(24) x0 += k1; x1 += k2 + 4u;
  TF_R(13) TF_R(15) TF_R(26) TF_R(6)  x0 += k2; x1 += k0 + 5u;
#undef TF_R
  o0 = x0; o1 = x1;
}

__device__ __forceinline__ float jax_erfinv(float x){
  float w = -log1pf(-x * x);
  float p;
  if (w < 5.0f) {
    w -= 2.5f;
    p = 2.81022636e-08f;
    p = fmaf(p, w, 3.43273939e-07f);
    p = fmaf(p, w, -3.5233877e-06f);
    p = fmaf(p, w, -4.39150654e-06f);
    p = fmaf(p, w, 0.00021858087f);
    p = fmaf(p, w, -0.00125372503f);
    p = fmaf(p, w, -0.00417768164f);
    p = fmaf(p, w, 0.246640727f);
    p = fmaf(p, w, 1.50140941f);
  } else {
    w = sqrtf(w) - 3.0f;
    p = -0.000200214257f;
    p = fmaf(p, w, 0.000100950558f);
    p = fmaf(p, w, 0.00134934322f);
    p = fmaf(p, w, -0.00367342844f);
    p = fmaf(p, w, 0.00573950773f);
    p = fmaf(p, w, -0.0076224613f);
    p = fmaf(p, w, 0.00943887047f);
    p = fmaf(p, w, 1.00167406f);
    p = fmaf(p, w, 2.83297682f);
  }
  return p * x;
}

// partitionable threefry: counter=(0,j), bits = o0^o1  (verified passing)
__device__ __forceinline__ float jax_normal_at(uint32_t j){
  uint32_t o0, o1;
  threefry2x32_k42(0u, j, o0, o1);
  uint32_t bits = o0 ^ o1;
  const float lo = -0.99999994f;
  float f = __uint_as_float((bits >> 9) | 0x3f800000u) - 1.0f;
  float fm = f * 1.99999994f;
  float u = fmaxf(lo, fm + lo);
  return 1.41421356f * jax_erfinv(u);
}

// ---------------- weight conversion kernel (ws path only) ----------------
struct ConvP { const float* src[11]; ushort_t* dst; };

__global__ void __launch_bounds__(64) convw(ConvP cp)
{
  int t = blockIdx.x;
  int lane = threadIdx.x;
  const int cum[12] = {0,65,156,247,338,429,520,611,702,793,884,1391};
  int mi = 0;
  #pragma unroll
  for (int i = 0; i < 11; ++i) if (t >= cum[i+1]) mi = i+1;
  int lt = t - cum[mi];
  int kb = lt / 13, nt = lt - kb*13;
  const float* S = cp.src[mi];
  int q = lane >> 4, m = lane & 15;
  int n = nt*16 + m;
  ushort_t* D = cp.dst + (size_t)t*512 + lane*8;
  #pragma unroll
  for (int j = 0; j < 8; ++j){
    int k = kb*32 + q*8 + j;
    float v = 0.f;
    if (n < 200){
      if (mi == 10){                       // W_bq: k<200 nb rows; 200..223 zero; >=224 obs rows
        if (k < 200) v = S[k*200+n];
        else if (k >= 224) v = S[(size_t)(k-24)*200+n];
      } else {
        int K = (mi == 0) ? 132 : 200;
        if (k < K) v = S[k*200+n];
      }
    }
    D[j] = f2bf(v);
  }
}

// ---------------- main fused kernel ----------------
struct MainP {
  const float* prev_state; const float* prev_action; const float* prev_belief;
  const float* observation; const float* nonterm;
  const float* b_sa; const float* b_ir; const float* b_iz; const float* b_in; const float* b_hn;
  const float* b_bp; const float* b_sp; const float* b_bq; const float* b_sq;
  const float* W[11];          // fp32 weights by mat id (direct path)
  const ushort_t* ws;
  float* out;
};

__device__ __forceinline__ short8 afrag(const ushort_t* buf, int m, int kb, int q){
  return *(const short8*)(buf + m*STR + kb*32 + q*8);
}

// ================= staged-pipeline machinery (WS path) =================
// Static schedule of 214 stage-steps; each step copies cnt (7 or 6) contiguous
// 1KB tiles from ws into a ring of THREE 7-tile LDS chunks. Prefetch runs
// 2 steps ahead; each step ends with a COUNTED vmcnt + raw s_barrier (T3/T4):
// never drain to 0 in steady state.
#define NSTEPS 214
#define STAGE_US 3584   // 7 tiles * 512 ushorts = 7168 B per chunk

struct Sched {
  short t0[NSTEPS]; signed char cnt[NSTEPS];
  constexpr Sched() : t0(), cnt() {
    int s = 0;
    // P2: SA, kb 0..4, halves (7+6)
    for (int kb = 0; kb < 5; ++kb){
      t0[s] = (short)(0 + kb*13);     cnt[s] = 7; ++s;
      t0[s] = (short)(0 + kb*13 + 7); cnt[s] = 6; ++s;
    }
    // GRU chunk1 (nt 0..6): kb 0..6 x mats IR,HR,IZ,HZ,IN,HN (ids 1..6, T0=65+91*(mt-1))
    for (int kb = 0; kb < 7; ++kb)
      for (int mt = 1; mt <= 6; ++mt){ t0[s] = (short)(65 + 91*(mt-1) + kb*13);     cnt[s] = 7; ++s; }
    // GRU chunk2 (nt 7..12)
    for (int kb = 0; kb < 7; ++kb)
      for (int mt = 1; mt <= 6; ++mt){ t0[s] = (short)(65 + 91*(mt-1) + kb*13 + 7); cnt[s] = 6; ++s; }
    // P5: BP (T0=611), kb 0..6
    for (int kb = 0; kb < 7; ++kb){
      t0[s] = (short)(611 + kb*13);     cnt[s] = 7; ++s;
      t0[s] = (short)(611 + kb*13 + 7); cnt[s] = 6; ++s;
    }
    // P6: SP (T0=702), kb 0..6
    for (int kb = 0; kb < 7; ++kb){
      t0[s] = (short)(702 + kb*13);     cnt[s] = 7; ++s;
      t0[s] = (short)(702 + kb*13 + 7); cnt[s] = 6; ++s;
    }
    // P7: BQ (T0=884), kb 0..38
    for (int kb = 0; kb < 39; ++kb){
      t0[s] = (short)(884 + kb*13);     cnt[s] = 7; ++s;
      t0[s] = (short)(884 + kb*13 + 7); cnt[s] = 6; ++s;
    }
    // P8: SQ (T0=793), kb 0..6
    for (int kb = 0; kb < 7; ++kb){
      t0[s] = (short)(793 + kb*13);     cnt[s] = 7; ++s;
      t0[s] = (short)(793 + kb*13 + 7); cnt[s] = 6; ++s;
    }
  }
};
__device__ constexpr Sched SCHED{};

// issue global_load_lds copies for one stage step into ring chunk step%3.
// Wave w handles tiles w, w+4. 16B/lane x 64 lanes = 1KB per instruction.
// LDS dest is wave-uniform base (HW writes base + lane*16); global src per-lane.
__device__ __forceinline__ void stage_issue(const ushort_t* ws, ushort_t* sbuf,
                                            int step, int w, int lane)
{
  if (step >= NSTEPS) return;
  const int t0 = SCHED.t0[step];
  const int cn = SCHED.cnt[step];
  ushort_t* dstb = sbuf + (step % 3) * STAGE_US;
  const ushort_t* srcb = ws + ((size_t)t0 << 9) + (lane << 3);
  #pragma unroll
  for (int r = 0; r < 2; ++r){
    int tt = w + r*4;
    if (tt < cn){
      __builtin_amdgcn_global_load_lds(
        (const __attribute__((address_space(1))) uint32_t*)(const void*)(srcb + (tt << 9)),
        (__attribute__((address_space(3)))       uint32_t*)(void*)(dstb + (tt << 9)),
        16, 0, 0);
    }
  }
}

// read one B-fragment (tile j of step's chunk) from the stage ring
__device__ __forceinline__ short8 sfrag(const ushort_t* sbuf, int step, int j, int lane){
  return *(const short8*)(sbuf + (step % 3) * STAGE_US + (j << 9) + (lane << 3));
}

// Counted-vmcnt step barrier: after consuming step sidx (whose chunk was
// guaranteed complete by the PREVIOUS step's sync) and issuing step sidx+2,
// wait until only my sidx+2 loads (+extra non-stage loads pinned last in
// issue order) remain in flight, then raw s_barrier. vmcnt retires in order,
// so this forces sidx+1's loads (and anything older: stores, etc.) complete
// while keeping the newest prefetch airborne. NEVER vmcnt(0) in steady state.
__device__ __forceinline__ void step_sync(int sidx, int w, int extra)
{
  int n2 = 0;
  if (sidx + 2 < NSTEPS){
    int cn = SCHED.cnt[sidx + 2];
    n2 = (w < cn ? 1 : 0) + ((w + 4) < cn ? 1 : 0);
  }
  int nw = n2 + extra;
  switch (nw){
    case 0:  asm volatile("s_waitcnt vmcnt(0)" ::: "memory"); break;
    case 1:  asm volatile("s_waitcnt vmcnt(1)" ::: "memory"); break;
    case 2:  asm volatile("s_waitcnt vmcnt(2)" ::: "memory"); break;
    case 3:  asm volatile("s_waitcnt vmcnt(3)" ::: "memory"); break;
    default: asm volatile("s_waitcnt vmcnt(4)" ::: "memory"); break;
  }
  __builtin_amdgcn_s_barrier();
}

// one kb of a 13-column-tile GEMM phase = 2 pipeline steps
__device__ __forceinline__ void gemm13_kb(const MainP& p, ushort_t* stageb, int& sidx,
    const ushort_t* asrc, floatx4 (&acc)[13], int kb, int m, int q, int lane, int w)
{
  short8 a = afrag(asrc, m, kb, q);
  stage_issue(p.ws, stageb, sidx+2, w, lane);
  #pragma unroll
  for (int j = 0; j < 7; ++j)
    acc[j] = __builtin_amdgcn_mfma_f32_16x16x32_bf16(a, sfrag(stageb, sidx, j, lane), acc[j], 0,0,0);
  step_sync(sidx, w, 0); ++sidx;
  stage_issue(p.ws, stageb, sidx+2, w, lane);
  #pragma unroll
  for (int j = 0; j < 6; ++j)
    acc[7+j] = __builtin_amdgcn_mfma_f32_16x16x32_bf16(a, sfrag(stageb, sidx, j, lane), acc[7+j], 0,0,0);
  step_sync(sidx, w, 0); ++sidx;
}

// GRU column-chunk, staged: per kb, 6 pipeline steps (IR,HR,IZ,HZ,IN,HN).
// Per-element accumulation order identical to the verified direct version.
template<int CNT, int NT0>
__device__ __forceinline__ void gru_chunk_staged(const MainP& p, ushort_t* stageb, int& sidx,
    const ushort_t* bufX, const ushort_t* bufH, int R0, int m, int q, int lane, int w,
    floatx4 (&nbv)[13])
{
  floatx4 aR[CNT], aZ[CNT], aXN[CNT], aHN[CNT];
  #pragma unroll
  for (int i = 0; i < CNT; ++i){
    int col = (NT0+i)*16 + m;
    float br = (col<200)? p.b_ir[col] : 0.f;
    float bz = (col<200)? p.b_iz[col] : 0.f;
    float bn = (col<200)? p.b_in[col] : 0.f;
    float bh = (col<200)? p.b_hn[col] : 0.f;
    aR[i]  = (floatx4){br,br,br,br};
    aZ[i]  = (floatx4){bz,bz,bz,bz};
    aXN[i] = (floatx4){bn,bn,bn,bn};
    aHN[i] = (floatx4){bh,bh,bh,bh};
  }
#define GRU_STEP(AV, ACC) \
  stage_issue(p.ws, stageb, sidx+2, w, lane); \
  _Pragma("unroll") \
  for (int i = 0; i < CNT; ++i) \
    ACC[i] = __builtin_amdgcn_mfma_f32_16x16x32_bf16(AV, sfrag(stageb, sidx, i, lane), ACC[i], 0,0,0); \
  step_sync(sidx, w, 0); ++sidx;

  #pragma unroll 1
  for (int kb = 0; kb < 7; ++kb){
    short8 ax = afrag(bufX, m, kb, q);
    short8 ah = afrag(bufH, m, kb, q);
    GRU_STEP(ax, aR)   // IR
    GRU_STEP(ah, aR)   // HR
    GRU_STEP(ax, aZ)   // IZ
    GRU_STEP(ah, aZ)   // HZ
    GRU_STEP(ax, aXN)  // IN
    GRU_STEP(ah, aHN)  // HN
  }
#undef GRU_STEP
  #pragma unroll
  for (int i = 0; i < CNT; ++i){
    int col = (NT0+i)*16 + m;
    if (col < 200){
      #pragma unroll
      for (int rg = 0; rg < 4; ++rg){
        int rowl = q*4 + rg;
        float rr = sigmf_(aR[i][rg]);
        float zz = sigmf_(aZ[i][rg]);
        float nn = tanhf(fmaf(rr, aHN[i][rg], aXN[i][rg]));
        float hv = bf2f(bufH[rowl*STR + col]);
        float nb = fmaf(zz, hv - nn, nn);
        nbv[NT0+i][rg] = nb;
        __builtin_nontemporal_store(nb, &p.out[(size_t)(R0+rowl)*200 + col]);
      }
    }
  }
}

// head epilogue: std transposed via fp32 LDS scratch. sdb is a PER-WAVE slab
// (bufH/bufX of this wave) — cross-lane within one wave only, so no barrier
// is needed (DS ops from one wave complete in order; compiler lgkmcnt's uses).
__device__ __forceinline__ void head_out(const floatx4* acc, float* sdb,
    float* o_state, float* o_mean, float* o_std, int R0, int m, int q)
{
  #pragma unroll
  for (int nt = 6; nt < 13; ++nt){
    int col = nt*16 + m;
    if (col >= 100 && col < 200){
      #pragma unroll
      for (int rg = 0; rg < 4; ++rg){
        int rowl = q*4 + rg;
        float sr = fmaxf(acc[nt][rg], 0.f);
        float sd = softplusf_(sr) + 0.1f;
        sdb[rowl*100 + (col-100)] = sd;
        __builtin_nontemporal_store(sd, &o_std[(size_t)(R0+rowl)*100 + (col-100)]);
      }
    }
  }
  #pragma unroll
  for (int nt = 0; nt < 7; ++nt){
    int col = nt*16 + m;
    if (col < 100){
      #pragma unroll
      for (int rg = 0; rg < 4; ++rg){
        int rowl = q*4 + rg;
        float mean = fmaxf(acc[nt][rg], 0.f);
        float sd = sdb[rowl*100 + col];
        float e = jax_normal_at((uint32_t)(R0+rowl)*100u + (uint32_t)col);
        __builtin_nontemporal_store(mean, &o_mean[(size_t)(R0+rowl)*100 + col]);
        __builtin_nontemporal_store(fmaf(sd, e, mean), &o_state[(size_t)(R0+rowl)*100 + col]);
      }
    }
  }
}

// =================== staged kernel (ws path) ===================
__global__ void __launch_bounds__(256, 2) rssm_staged(MainP p)
{
  // 8 per-wave slabs (59392 B) + ring-3 stage (21504 B) = 80896 B <= 81920
  // -> 2 blocks/CU (161792 <= 163840 B CU LDS).
  __shared__ __align__(16) ushort_t lds[8*SLAB + 3*STAGE_US];

  const int tid  = threadIdx.x;
  const int w    = tid >> 6;
  const int lane = tid & 63;
  const int q    = lane >> 4;
  const int m    = lane & 15;
  const int R0   = blockIdx.x * 64 + w * 16;

  ushort_t* bufX   = lds + w * 2 * SLAB;
  ushort_t* bufH   = bufX + SLAB;
  ushort_t* stageb = lds + 8*SLAB;
  int sidx = 0;

  // prologue: issue stage steps 0 and 1 (ring chunks 0,1)
  stage_issue(p.ws, stageb, 0, w, lane);
  stage_issue(p.ws, stageb, 1, w, lane);

  // ---- phase 1: stage [s*nt | a | 0] -> bufX (k 0..159); zero bufH pad cols
  for (int t = lane; t < 16*160; t += 64){
    int rr = t / 160, cc = t - rr*160;
    int grow = R0 + rr;
    float v = 0.f;
    if (cc < 100)      v = p.prev_state[(size_t)grow*100 + cc] * p.nonterm[grow];
    else if (cc < 132) v = p.prev_action[(size_t)grow*32 + (cc-100)];
    bufX[rr*STR + cc] = f2bf(v);
  }
  for (int t = lane; t < 16*24; t += 64){
    int rr = t / 24, cc = 200 + (t - rr*24);
    bufH[rr*STR + cc] = 0;
  }
  // one full drain + barrier before entering the pipeline (steps 0,1 land here)
  asm volatile("s_waitcnt vmcnt(0)" ::: "memory");
  __builtin_amdgcn_s_barrier();

  // ---- phase 2: SA gemm -> h (relu) -> bufH   (steps 0..9)
  {
    floatx4 acc[13];
    #pragma unroll
    for (int nt = 0; nt < 13; ++nt){
      int col = nt*16 + m;
      float bv = (col<200)? p.b_sa[col] : 0.f;
      acc[nt] = (floatx4){bv,bv,bv,bv};
    }
    #pragma unroll 1
    for (int kb = 0; kb < 5; ++kb)
      gemm13_kb(p, stageb, sidx, bufX, acc, kb, m, q, lane, w);
    #pragma unroll
    for (int nt = 0; nt < 13; ++nt){
      int col = nt*16 + m;
      if (col < 200){
        #pragma unroll
        for (int rg = 0; rg < 4; ++rg)
          bufH[(q*4+rg)*STR + col] = f2bf(fmaxf(acc[nt][rg], 0.f));
      }
    }
  }

  // ---- phase 3: stage x = prev_belief -> bufX (zero pad to 223). Per-wave slab:
  // no barrier needed; pipeline barriers keep waves aligned.
  for (int t = lane; t < 16*224; t += 64){
    int rr = t / 224, cc = t - rr*224;
    float v = 0.f;
    if (cc < 200)
      v = __builtin_nontemporal_load(&p.prev_belief[(size_t)(R0+rr)*200 + cc]);
    bufX[rr*STR + cc] = f2bf(v);
  }

  // ---- phase 4: GRU (steps 10..51 chunk1, 52..93 chunk2)
  floatx4 nbv[13];
  gru_chunk_staged<7,0>(p, stageb, sidx, bufX, bufH, R0, m, q, lane, w, nbv);
  gru_chunk_staged<6,7>(p, stageb, sidx, bufX, bufH, R0, m, q, lane, w, nbv);

  // ---- stage nb -> bufX directly from registers (bf16); pads still zero
  #pragma unroll
  for (int nt = 0; nt < 13; ++nt){
    int col = nt*16 + m;
    if (col < 200){
      #pragma unroll
      for (int rg = 0; rg < 4; ++rg)
        bufX[(q*4+rg)*STR + col] = f2bf(nbv[nt][rg]);
    }
  }

  // ---- phase 5: bp gemm -> hp -> bufH   (steps 94..107)
  {
    floatx4 acc[13];
    #pragma unroll
    for (int nt = 0; nt < 13; ++nt){
      int col = nt*16 + m;
      float bv = (col<200)? p.b_bp[col] : 0.f;
      acc[nt] = (floatx4){bv,bv,bv,bv};
    }
    #pragma unroll 1
    for (int kb = 0; kb < 7; ++kb)
      gemm13_kb(p, stageb, sidx, bufX, acc, kb, m, q, lane, w);
    #pragma unroll
    for (int nt = 0; nt < 13; ++nt){
      int col = nt*16 + m;
      if (col < 200){
        #pragma unroll
        for (int rg = 0; rg < 4; ++rg)
          bufH[(q*4+rg)*STR + col] = f2bf(fmaxf(acc[nt][rg], 0.f));
      }
    }
  }

  // ---- phase 6: sp gemm -> prior outputs (fp32 scratch in bufH)  (steps 108..121)
  {
    floatx4 acc[13];
    #pragma unroll
    for (int nt = 0; nt < 13; ++nt){
      int col = nt*16 + m;
      float bv = (col<200)? p.b_sp[col] : 0.f;
      acc[nt] = (floatx4){bv,bv,bv,bv};
    }
    #pragma unroll 1
    for (int kb = 0; kb < 7; ++kb)
      gemm13_kb(p, stageb, sidx, bufH, acc, kb, m, q, lane, w);
    head_out(acc, (float*)bufH,
             p.out + (size_t)BATCH*200, p.out + (size_t)BATCH*300, p.out + (size_t)BATCH*400,
             R0, m, q);
  }

  // ---- phase 7: hq gemm (nb A-frags from bufX, obs streamed from HBM)  (steps 122..199)
  {
    floatx4 acc[13];
    #pragma unroll
    for (int nt = 0; nt < 13; ++nt){
      int col = nt*16 + m;
      float bv = (col<200)? p.b_bq[col] : 0.f;
      acc[nt] = (floatx4){bv,bv,bv,bv};
    }
    #pragma unroll 1
    for (int kb = 0; kb < 7; ++kb)
      gemm13_kb(p, stageb, sidx, bufX, acc, kb, m, q, lane, w);

    const float* orow_base = p.observation + (size_t)(R0+m)*1024;
    floatx4 o1 = __builtin_nontemporal_load((const floatx4*)(orow_base + q*8));
    floatx4 o2 = __builtin_nontemporal_load((const floatx4*)(orow_base + q*8 + 4));
    #pragma unroll 1
    for (int kb = 7; kb < 39; ++kb){
      short8 ao;
      ao[0] = (short)f2bf(o1[0]); ao[1] = (short)f2bf(o1[1]);
      ao[2] = (short)f2bf(o1[2]); ao[3] = (short)f2bf(o1[3]);
      ao[4] = (short)f2bf(o2[0]); ao[5] = (short)f2bf(o2[1]);
      ao[6] = (short)f2bf(o2[2]); ao[7] = (short)f2bf(o2[3]);
      // step A
      stage_issue(p.ws, stageb, sidx+2, w, lane);
      #pragma unroll
      for (int j = 0; j < 7; ++j)
        acc[j] = __builtin_amdgcn_mfma_f32_16x16x32_bf16(ao, sfrag(stageb, sidx, j, lane), acc[j], 0,0,0);
      step_sync(sidx, w, 0); ++sidx;
      // step B: next-kb obs loads pinned BEFORE the stage issue, so the stage
      // loads are the newest vmcnt entries and the counted wait (+2) keeps
      // both obs loads and the stage prefetch in flight across the barrier.
      floatx4 nn1 = {0,0,0,0}, nn2 = {0,0,0,0};
      int ex = 0;
      if (kb < 38){
        const float* nr = orow_base + ((kb+1)*32 - 224) + q*8;
        nn1 = __builtin_nontemporal_load((const floatx4*)(nr));
        nn2 = __builtin_nontemporal_load((const floatx4*)(nr + 4));
        ex = 2;
      }
      __builtin_amdgcn_sched_barrier(0);
      stage_issue(p.ws, stageb, sidx+2, w, lane);
      #pragma unroll
      for (int j = 0; j < 6; ++j)
        acc[7+j] = __builtin_amdgcn_mfma_f32_16x16x32_bf16(ao, sfrag(stageb, sidx, j, lane), acc[7+j], 0,0,0);
      step_sync(sidx, w, ex); ++sidx;
      o1 = nn1; o2 = nn2;
    }
    // hq -> bufH + re-zero pad cols (phase-6 scratch clobbered them)
    #pragma unroll
    for (int nt = 0; nt < 13; ++nt){
      int col = nt*16 + m;
      if (col < 200){
        #pragma unroll
        for (int rg = 0; rg < 4; ++rg)
          bufH[(q*4+rg)*STR + col] = f2bf(fmaxf(acc[nt][rg], 0.f));
      }
    }
    for (int t = lane; t < 16*24; t += 64){
      int rr = t / 24, cc = 200 + (t - rr*24);
      bufH[rr*STR + cc] = 0;
    }
  }

  // ---- phase 8: sq gemm -> posterior outputs (fp32 scratch in bufX)  (steps 200..213)
  {
    floatx4 acc[13];
    #pragma unroll
    for (int nt = 0; nt < 13; ++nt){
      int col = nt*16 + m;
      float bv = (col<200)? p.b_sq[col] : 0.f;
      acc[nt] = (floatx4){bv,bv,bv,bv};
    }
    #pragma unroll 1
    for (int kb = 0; kb < 7; ++kb)
      gemm13_kb(p, stageb, sidx, bufH, acc, kb, m, q, lane, w);
    head_out(acc, (float*)bufX,
             p.out + (size_t)BATCH*500, p.out + (size_t)BATCH*600, p.out + (size_t)BATCH*700,
             R0, m, q);
  }
}

// =================== direct fallback (no ws) — verified path ===================
template<int MAT>
__device__ __forceinline__ short8 bfr0(const MainP& p, int kb, int nt, int lane, int q, int m){
  int n = nt*16 + m;
  const float* S = p.W[MAT];
  uint32_t u[8];
  #pragma unroll
  for (int j = 0; j < 8; ++j){
    int k = kb*32 + q*8 + j;
    int srow;
    if (MAT == M_BQ) srow = (k < 200) ? k : ((k >= 224) ? k - 24 : -1);
    else             srow = (k < KLIM[MAT]) ? k : -1;
    float v = (srow >= 0 && n < 200) ? S[(size_t)srow*200 + n] : 0.f;
    u[j] = __float_as_uint(v);
  }
  short8 r;
  #pragma unroll
  for (int j = 0; j < 8; ++j) r[j] = (short)(u[j] >> 16);
  return r;
}

template<int CNT, int NT0>
__device__ __forceinline__ void gru_chunk0(const MainP& p,
    const ushort_t* bufX, const ushort_t* bufH, int R0, int m, int q, int lane,
    floatx4 (&nbv)[13])
{
  floatx4 aR[CNT], aZ[CNT], aXN[CNT], aHN[CNT];
  #pragma unroll
  for (int i = 0; i < CNT; ++i){
    int col = (NT0+i)*16 + m;
    float br = (col<200)? p.b_ir[col] : 0.f;
    float bz = (col<200)? p.b_iz[col] : 0.f;
    float bn = (col<200)? p.b_in[col] : 0.f;
    float bh = (col<200)? p.b_hn[col] : 0.f;
    aR[i]  = (floatx4){br,br,br,br};
    aZ[i]  = (floatx4){bz,bz,bz,bz};
    aXN[i] = (floatx4){bn,bn,bn,bn};
    aHN[i] = (floatx4){bh,bh,bh,bh};
  }
  #pragma unroll 1
  for (int kb = 0; kb < 7; ++kb){
    short8 ax = afrag(bufX, m, kb, q);
    short8 ah = afrag(bufH, m, kb, q);
    #pragma unroll
    for (int i = 0; i < CNT; ++i){
      int nt = NT0 + i;
      aR[i]  = __builtin_amdgcn_mfma_f32_16x16x32_bf16(ax, bfr0<M_IR>(p,kb,nt,lane,q,m), aR[i], 0,0,0);
      aR[i]  = __builtin_amdgcn_mfma_f32_16x16x32_bf16(ah, bfr0<M_HR>(p,kb,nt,lane,q,m), aR[i], 0,0,0);
      aZ[i]  = __builtin_amdgcn_mfma_f32_16x16x32_bf16(ax, bfr0<M_IZ>(p,kb,nt,lane,q,m), aZ[i], 0,0,0);
      aZ[i]  = __builtin_amdgcn_mfma_f32_16x16x32_bf16(ah, bfr0<M_HZ>(p,kb,nt,lane,q,m), aZ[i], 0,0,0);
      aXN[i] = __builtin_amdgcn_mfma_f32_16x16x32_bf16(ax, bfr0<M_IN>(p,kb,nt,lane,q,m), aXN[i], 0,0,0);
      aHN[i] = __builtin_amdgcn_mfma_f32_16x16x32_bf16(ah, bfr0<M_HN>(p,kb,nt,lane,q,m), aHN[i], 0,0,0);
    }
  }
  #pragma unroll
  for (int i = 0; i < CNT; ++i){
    int col = (NT0+i)*16 + m;
    if (col < 200){
      #pragma unroll
      for (int rg = 0; rg < 4; ++rg){
        int rowl = q*4 + rg;
        float rr = sigmf_(aR[i][rg]);
        float zz = sigmf_(aZ[i][rg]);
        float nn = tanhf(fmaf(rr, aHN[i][rg], aXN[i][rg]));
        float hv = bf2f(bufH[rowl*STR + col]);
        float nb = fmaf(zz, hv - nn, nn);
        nbv[NT0+i][rg] = nb;
        __builtin_nontemporal_store(nb, &p.out[(size_t)(R0+rowl)*200 + col]);
      }
    }
  }
}

__global__ void __launch_bounds__(256, 2) rssm_direct(MainP p)
{
  __shared__ __align__(16) ushort_t lds[4 * 2 * SLAB];

  const int tid  = threadIdx.x;
  const int w    = tid >> 6;
  const int lane = tid & 63;
  const int q    = lane >> 4;
  const int m    = lane & 15;
  const int R0   = blockIdx.x * 64 + w * 16;

  ushort_t* bufX = lds + w * 2 * SLAB;
  ushort_t* bufH = bufX + SLAB;

  for (int t = lane; t < 16*160; t += 64){
    int rr = t / 160, cc = t - rr*160;
    int grow = R0 + rr;
    float v = 0.f;
    if (cc < 100)      v = p.prev_state[(size_t)grow*100 + cc] * p.nonterm[grow];
    else if (cc < 132) v = p.prev_action[(size_t)grow*32 + (cc-100)];
    bufX[rr*STR + cc] = f2bf(v);
  }
  for (int t = lane; t < 16*24; t += 64){
    int rr = t / 24, cc = 200 + (t - rr*24);
    bufH[rr*STR + cc] = 0;
  }
  __syncthreads();

  {
    floatx4 acc[13];
    #pragma unroll
    for (int nt = 0; nt < 13; ++nt){
      int col = nt*16 + m;
      float bv = (col<200)? p.b_sa[col] : 0.f;
      acc[nt] = (floatx4){bv,bv,bv,bv};
    }
    #pragma unroll 1
    for (int kb = 0; kb < 5; ++kb){
      short8 a = afrag(bufX, m, kb, q);
      #pragma unroll
      for (int nt = 0; nt < 13; ++nt)
        acc[nt] = __builtin_amdgcn_mfma_f32_16x16x32_bf16(a, bfr0<M_SA>(p,kb,nt,lane,q,m), acc[nt], 0,0,0);
    }
    #pragma unroll
    for (int nt = 0; nt < 13; ++nt){
      int col = nt*16 + m;
      if (col < 200){
        #pragma unroll
        for (int rg = 0; rg < 4; ++rg)
          bufH[(q*4+rg)*STR + col] = f2bf(fmaxf(acc[nt][rg], 0.f));
      }
    }
  }

  for (int t = lane; t < 16*224; t += 64){
    int rr = t / 224, cc = t - rr*224;
    float v = 0.f;
    if (cc < 200)
      v = __builtin_nontemporal_load(&p.prev_belief[(size_t)(R0+rr)*200 + cc]);
    bufX[rr*STR + cc] = f2bf(v);
  }
  __syncthreads();

  floatx4 nbv[13];
  gru_chunk0<7,0>(p, bufX, bufH, R0, m, q, lane, nbv);
  gru_chunk0<6,7>(p, bufX, bufH, R0, m, q, lane, nbv);

  #pragma unroll
  for (int nt = 0; nt < 13; ++nt){
    int col = nt*16 + m;
    if (col < 200){
      #pragma unroll
      for (int rg = 0; rg < 4; ++rg)
        bufX[(q*4+rg)*STR + col] = f2bf(nbv[nt][rg]);
    }
  }

  {
    floatx4 acc[13];
    #pragma unroll
    for (int nt = 0; nt < 13; ++nt){
      int col = nt*16 + m;
      float bv = (col<200)? p.b_bp[col] : 0.f;
      acc[nt] = (floatx4){bv,bv,bv,bv};
    }
    #pragma unroll 1
    for (int kb = 0; kb < 7; ++kb){
      short8 a = afrag(bufX, m, kb, q);
      #pragma unroll
      for (int nt = 0; nt < 13; ++nt)
        acc[nt] = __builtin_amdgcn_mfma_f32_16x16x32_bf16(a, bfr0<M_BP>(p,kb,nt,lane,q,m), acc[nt], 0,0,0);
    }
    #pragma unroll
    for (int nt = 0; nt < 13; ++nt){
      int col = nt*16 + m;
      if (col < 200){
        #pragma unroll
        for (int rg = 0; rg < 4; ++rg)
          bufH[(q*4+rg)*STR + col] = f2bf(fmaxf(acc[nt][rg], 0.f));
      }
    }
  }
  __syncthreads();

  {
    floatx4 acc[13];
    #pragma unroll
    for (int nt = 0; nt < 13; ++nt){
      int col = nt*16 + m;
      float bv = (col<200)? p.b_sp[col] : 0.f;
      acc[nt] = (floatx4){bv,bv,bv,bv};
    }
    #pragma unroll 1
    for (int kb = 0; kb < 7; ++kb){
      short8 a = afrag(bufH, m, kb, q);
      #pragma unroll
      for (int nt = 0; nt < 13; ++nt)
        acc[nt] = __builtin_amdgcn_mfma_f32_16x16x32_bf16(a, bfr0<M_SP>(p,kb,nt,lane,q,m), acc[nt], 0,0,0);
    }
    head_out(acc, (float*)bufH,
             p.out + (size_t)BATCH*200, p.out + (size_t)BATCH*300, p.out + (size_t)BATCH*400,
             R0, m, q);
  }
  __syncthreads();

  {
    floatx4 acc[13];
    #pragma unroll
    for (int nt = 0; nt < 13; ++nt){
      int col = nt*16 + m;
      float bv = (col<200)? p.b_bq[col] : 0.f;
      acc[nt] = (floatx4){bv,bv,bv,bv};
    }
    #pragma unroll 1
    for (int kb = 0; kb < 7; ++kb){
      short8 a = afrag(bufX, m, kb, q);
      #pragma unroll
      for (int nt = 0; nt < 13; ++nt)
        acc[nt] = __builtin_amdgcn_mfma_f32_16x16x32_bf16(a, bfr0<M_BQ>(p,kb,nt,lane,q,m), acc[nt], 0,0,0);
    }
    const float* orow_base = p.observation + (size_t)(R0+m)*1024;
    #pragma unroll 1
    for (int kb = 7; kb < 39; ++kb){
      const float* orow = orow_base + (kb*32 - 224) + q*8;
      floatx4 o1 = __builtin_nontemporal_load((const floatx4*)(orow));
      floatx4 o2 = __builtin_nontemporal_load((const floatx4*)(orow + 4));
      short8 ao;
      ao[0] = (short)f2bf(o1[0]); ao[1] = (short)f2bf(o1[1]);
      ao[2] = (short)f2bf(o1[2]); ao[3] = (short)f2bf(o1[3]);
      ao[4] = (short)f2bf(o2[0]); ao[5] = (short)f2bf(o2[1]);
      ao[6] = (short)f2bf(o2[2]); ao[7] = (short)f2bf(o2[3]);
      #pragma unroll
      for (int nt = 0; nt < 13; ++nt)
        acc[nt] = __builtin_amdgcn_mfma_f32_16x16x32_bf16(ao, bfr0<M_BQ>(p,kb,nt,lane,q,m), acc[nt], 0,0,0);
    }
    #pragma unroll
    for (int nt = 0; nt < 13; ++nt){
      int col = nt*16 + m;
      if (col < 200){
        #pragma unroll
        for (int rg = 0; rg < 4; ++rg)
          bufH[(q*4+rg)*STR + col] = f2bf(fmaxf(acc[nt][rg], 0.f));
      }
    }
    for (int t = lane; t < 16*24; t += 64){
      int rr = t / 24, cc = 200 + (t - rr*24);
      bufH[rr*STR + cc] = 0;
    }
  }
  __syncthreads();

  {
    floatx4 acc[13];
    #pragma unroll
    for (int nt = 0; nt < 13; ++nt){
      int col = nt*16 + m;
      float bv = (col<200)? p.b_sq[col] : 0.f;
      acc[nt] = (floatx4){bv,bv,bv,bv};
    }
    #pragma unroll 1
    for (int kb = 0; kb < 7; ++kb){
      short8 a = afrag(bufH, m, kb, q);
      #pragma unroll
      for (int nt = 0; nt < 13; ++nt)
        acc[nt] = __builtin_amdgcn_mfma_f32_16x16x32_bf16(a, bfr0<M_SQ>(p,kb,nt,lane,q,m), acc[nt], 0,0,0);
    }
    head_out(acc, (float*)bufX,
             p.out + (size_t)BATCH*500, p.out + (size_t)BATCH*600, p.out + (size_t)BATCH*700,
             R0, m, q);
  }
}

extern "C" void kernel_launch(void* const* d_in, const int* in_sizes, int n_in,
                              void* d_out, int out_size, void* d_ws, size_t ws_size,
                              hipStream_t stream)
{
  MainP p;
  p.prev_state  = (const float*)d_in[0];
  p.prev_action = (const float*)d_in[1];
  p.prev_belief = (const float*)d_in[2];
  p.observation = (const float*)d_in[3];
  p.nonterm     = (const float*)d_in[4];
  p.b_sa = (const float*)d_in[6];
  p.b_ir = (const float*)d_in[8];
  p.b_iz = (const float*)d_in[10];
  p.b_in = (const float*)d_in[12];
  p.b_hn = (const float*)d_in[16];
  p.b_bp = (const float*)d_in[18];
  p.b_sp = (const float*)d_in[20];
  p.b_bq = (const float*)d_in[22];
  p.b_sq = (const float*)d_in[24];
  p.W[M_SA] = (const float*)d_in[5];
  p.W[M_IR] = (const float*)d_in[7];
  p.W[M_HR] = (const float*)d_in[13];
  p.W[M_IZ] = (const float*)d_in[9];
  p.W[M_HZ] = (const float*)d_in[14];
  p.W[M_IN] = (const float*)d_in[11];
  p.W[M_HN] = (const float*)d_in[15];
  p.W[M_BP] = (const float*)d_in[17];
  p.W[M_SP] = (const float*)d_in[19];
  p.W[M_SQ] = (const float*)d_in[23];
  p.W[M_BQ] = (const float*)d_in[21];
  p.ws   = (const ushort_t*)d_ws;
  p.out  = (float*)d_out;

  bool use_ws = (ws_size >= (size_t)TOT_TILES * 1024u);
  if (use_ws){
    ConvP cp;
    cp.src[0]  = p.W[M_SA]; cp.src[1]  = p.W[M_IR]; cp.src[2]  = p.W[M_HR];
    cp.src[3]  = p.W[M_IZ]; cp.src[4]  = p.W[M_HZ]; cp.src[5]  = p.W[M_IN];
    cp.src[6]  = p.W[M_HN]; cp.src[7]  = p.W[M_BP]; cp.src[8]  = p.W[M_SP];
    cp.src[9]  = p.W[M_SQ]; cp.src[10] = p.W[M_BQ];
    cp.dst     = (ushort_t*)d_ws;
    convw<<<TOT_TILES, 64, 0, stream>>>(cp);
    rssm_staged<<<512, 256, 0, stream>>>(p);
  } else {
    rssm_direct<<<512, 256, 0, stream>>>(p);
  }
}